// Round 1
// baseline (289.813 us; speedup 1.0000x reference)
//
#include <hip/hip_runtime.h>
#include <hip/hip_bf16.h>

typedef __attribute__((ext_vector_type(8))) short short8;
typedef __attribute__((ext_vector_type(4))) float f32x4;

#define L_DIM 2048
#define K_NBR 48
#define H_DIM 128

__device__ inline short f2bf(float f) {
    unsigned u = __builtin_bit_cast(unsigned, f);
    u += 0x7fffu + ((u >> 16) & 1u);
    return (short)(u >> 16);
}

__device__ inline float gelu_exact(float x) {
    return 0.5f * x * (1.0f + erff(x * 0.70710678118654752f));
}

__device__ inline float wred(float s) {
#pragma unroll
    for (int o = 32; o; o >>= 1) s += __shfl_xor(s, o, 64);
    return s;
}

// ---------------- pack a KxN fp32 weight into bf16 MFMA-B fragment order ----
// B-frag for mfma_f32_16x16x32_bf16: lane l holds B[k=(l>>4)*8+j][n=l&15].
// Packed layout: fragment index (nt*Kt + kt)*64 + lane, 8 bf16 each -> lane
// loads are fully coalesced (64 lanes x 16B = 1KB contiguous).
__global__ void pack_w_kernel(const float* __restrict__ W, short* __restrict__ out,
                              int Kt /*K/32*/, int N) {
    int i = blockIdx.x * 256 + threadIdx.x;
    int total = (N >> 4) * Kt * 64;
    if (i >= total) return;
    int lane = i & 63;
    int tile = i >> 6;
    int kt = tile % Kt;
    int nt = tile / Kt;
    int n = nt * 16 + (lane & 15);
    int k0 = kt * 32 + (lane >> 4) * 8;
    short8 v;
#pragma unroll
    for (int j = 0; j < 8; ++j) v[j] = f2bf(W[(size_t)(k0 + j) * N + n]);
    *(short8*)(out + (size_t)i * 8) = v;
}

// ---------------- per-node precompute: Ys = x@Wa + bias, Yn = x@Wc ----------
// Wa = rows 0..127 of W (self part), Wc = rows 256..383 (neighbor part).
__global__ __launch_bounds__(256) void node_pre_kernel(
    const float* __restrict__ hV, const float* __restrict__ W,
    const float* __restrict__ bias, float* __restrict__ Ys, float* __restrict__ Yn) {
    int n0 = blockIdx.x * 8;
    int tid = threadIdx.x;
    int col = tid & 127;
    int half = tid >> 7;
    __shared__ float X[8 * 128];
    for (int i = tid; i < 1024; i += 256) X[i] = hV[(size_t)n0 * 128 + i];
    __syncthreads();
    const float* Wp = W + (half ? 256 * 128 : 0);
    float acc[8];
#pragma unroll
    for (int r = 0; r < 8; ++r) acc[r] = 0.f;
    for (int k = 0; k < 128; ++k) {
        float wv = Wp[(size_t)k * 128 + col];
#pragma unroll
        for (int r = 0; r < 8; ++r) acc[r] += X[r * 128 + k] * wv;
    }
    float bb = half ? 0.f : bias[col];
    float* dst = half ? Yn : Ys;
#pragma unroll
    for (int r = 0; r < 8; ++r) dst[(size_t)(n0 + r) * 128 + col] = acc[r] + bb;
}

// ---------------- 48x128 @ 128x128 MFMA GEMM (per 4-wave block) -------------
// A in LDS, bf16, XOR-swizzled: byte = row*256 + ((2*col) ^ ((row&7)<<4)).
// Each wave owns 32 output cols (2 n-tiles), all 3 m-tiles.
__device__ inline void gemm48(const short* A_sw, const short8* __restrict__ Bp,
                              int w, int lane, f32x4 acc[3][2]) {
#pragma unroll
    for (int mt = 0; mt < 3; ++mt)
#pragma unroll
        for (int n2 = 0; n2 < 2; ++n2) acc[mt][n2] = (f32x4){0.f, 0.f, 0.f, 0.f};
#pragma unroll
    for (int kt = 0; kt < 4; ++kt) {
        short8 a[3];
        int kb = (kt * 32 + (lane >> 4) * 8) * 2;
#pragma unroll
        for (int mt = 0; mt < 3; ++mt) {
            int row = mt * 16 + (lane & 15);
            a[mt] = *(const short8*)((const char*)A_sw + row * 256 + (kb ^ ((row & 7) << 4)));
        }
#pragma unroll
        for (int n2 = 0; n2 < 2; ++n2) {
            short8 bf = Bp[((w * 2 + n2) * 4 + kt) * 64 + lane];
#pragma unroll
            for (int mt = 0; mt < 3; ++mt)
                acc[mt][n2] = __builtin_amdgcn_mfma_f32_16x16x32_bf16(a[mt], bf, acc[mt][n2], 0, 0, 0);
        }
    }
}

// ---------------- node message MLP + masked mean + LN1 ----------------------
__global__ __launch_bounds__(256) void node_msg_kernel(
    const float* __restrict__ hV, const float* __restrict__ hE,
    const int* __restrict__ Eidx, const float* __restrict__ maskAtt,
    const short8* __restrict__ W1bp, const short8* __restrict__ W2p,
    const short8* __restrict__ W3p, const float* __restrict__ b2,
    const float* __restrict__ b3, const float* __restrict__ Ysg,
    const float* __restrict__ Yng, const float* __restrict__ g1,
    const float* __restrict__ be1, float* __restrict__ hv1out) {
    const int node = blockIdx.x;
    const int bb = node >> 11;
    const int tid = threadIdx.x;
    const int lane = tid & 63, w = tid >> 6;

    __shared__ __align__(16) short A_sw[48 * 128];
    __shared__ float Yg[48 * 132];
    __shared__ float Ysh[128];
    __shared__ float red[8];

    // stage h_E -> bf16 swizzled LDS
    const float* Eb = hE + (size_t)node * 6144;
#pragma unroll
    for (int i = 0; i < 3; ++i) {
        int e = tid + i * 256;
        int r = e >> 4, c0 = (e & 15) * 8;
        float4 f0 = *(const float4*)(Eb + r * 128 + c0);
        float4 f1 = *(const float4*)(Eb + r * 128 + c0 + 4);
        short8 v;
        v[0] = f2bf(f0.x); v[1] = f2bf(f0.y); v[2] = f2bf(f0.z); v[3] = f2bf(f0.w);
        v[4] = f2bf(f1.x); v[5] = f2bf(f1.y); v[6] = f2bf(f1.z); v[7] = f2bf(f1.w);
        *(short8*)((char*)A_sw + r * 256 + ((c0 * 2) ^ ((r & 7) << 4))) = v;
    }
    if (tid < 128) Ysh[tid] = Ysg[(size_t)node * 128 + tid];
    // gather neighbor-part rows Yn[E_idx]
#pragma unroll 4
    for (int i = 0; i < 24; ++i) {
        int e = tid + i * 256;
        int r = e >> 7, c = e & 127;
        int idx = Eidx[node * 48 + r];
        Yg[r * 132 + c] = Yng[((size_t)bb * 2048 + idx) * 128 + c];
    }
    __syncthreads();

    f32x4 acc[3][2];
    // layer 1: h_E @ W1b (+Ys +Yn[idx]), gelu
    gemm48(A_sw, W1bp, w, lane, acc);
    __syncthreads();
#pragma unroll
    for (int mt = 0; mt < 3; ++mt)
#pragma unroll
        for (int n2 = 0; n2 < 2; ++n2) {
            int col = (w * 2 + n2) * 16 + (lane & 15);
#pragma unroll
            for (int i = 0; i < 4; ++i) {
                int row = mt * 16 + (lane >> 4) * 4 + i;
                float v = acc[mt][n2][i] + Ysh[col] + Yg[row * 132 + col];
                v = gelu_exact(v);
                *(short*)((char*)A_sw + row * 256 + ((col * 2) ^ ((row & 7) << 4))) = f2bf(v);
            }
        }
    __syncthreads();
    // layer 2
    gemm48(A_sw, W2p, w, lane, acc);
    __syncthreads();
#pragma unroll
    for (int mt = 0; mt < 3; ++mt)
#pragma unroll
        for (int n2 = 0; n2 < 2; ++n2) {
            int col = (w * 2 + n2) * 16 + (lane & 15);
            float bv = b2[col];
#pragma unroll
            for (int i = 0; i < 4; ++i) {
                int row = mt * 16 + (lane >> 4) * 4 + i;
                float v = gelu_exact(acc[mt][n2][i] + bv);
                *(short*)((char*)A_sw + row * 256 + ((col * 2) ^ ((row & 7) << 4))) = f2bf(v);
            }
        }
    __syncthreads();
    // layer 3: + b3, mask, stash to LDS for column sum
    gemm48(A_sw, W3p, w, lane, acc);
#pragma unroll
    for (int mt = 0; mt < 3; ++mt)
#pragma unroll
        for (int n2 = 0; n2 < 2; ++n2) {
            int col = (w * 2 + n2) * 16 + (lane & 15);
            float bv = b3[col];
#pragma unroll
            for (int i = 0; i < 4; ++i) {
                int row = mt * 16 + (lane >> 4) * 4 + i;
                float v = (acc[mt][n2][i] + bv) * maskAtt[node * 48 + row];
                Yg[row * 132 + col] = v;
            }
        }
    __syncthreads();

    // masked sum over K, /30, residual, LN1
    float u = 0.f;
    if (tid < 128) {
        float s = 0.f;
        for (int r = 0; r < 48; ++r) s += Yg[r * 132 + tid];
        u = hV[(size_t)node * 128 + tid] + s * (1.0f / 30.0f);
    }
    float sv = wred((tid < 128) ? u : 0.f);
    if (lane == 0) red[w] = sv;
    __syncthreads();
    float mu = (red[0] + red[1]) * (1.0f / 128.0f);
    float d = (tid < 128) ? (u - mu) : 0.f;
    float vv = wred(d * d);
    if (lane == 0) red[4 + w] = vv;
    __syncthreads();
    float var = (red[4] + red[5]) * (1.0f / 128.0f);
    if (tid < 128) {
        float rs = rsqrtf(var + 1e-5f);
        hv1out[(size_t)node * 128 + tid] = d * rs * g1[tid] + be1[tid];
    }
}

// ---------------- position-wise FFN + LN2 + mask_V ---------------------------
__global__ __launch_bounds__(256) void ffn_kernel(
    const float* __restrict__ hv1, const float* __restrict__ Win,
    const float* __restrict__ binp, const float* __restrict__ Wout,
    const float* __restrict__ bout, const float* __restrict__ g2,
    const float* __restrict__ be2, const float* __restrict__ maskV,
    float* __restrict__ hVout) {
    int n0 = blockIdx.x * 16;
    int tid = threadIdx.x, lane = tid & 63, w = tid >> 6;
    __shared__ float X[16 * 128];
    __shared__ float Hm[16 * 512];
    for (int i = tid; i < 2048; i += 256) X[i] = hv1[(size_t)n0 * 128 + i];
    __syncthreads();
    // X @ Win + bin, gelu -> Hm
#pragma unroll
    for (int half = 0; half < 2; ++half) {
        int col = half * 256 + tid;
        float acc[16];
#pragma unroll
        for (int r = 0; r < 16; ++r) acc[r] = 0.f;
        for (int k = 0; k < 128; ++k) {
            float wv = Win[(size_t)k * 512 + col];
#pragma unroll
            for (int r = 0; r < 16; ++r) acc[r] += X[r * 128 + k] * wv;
        }
        float bv = binp[col];
#pragma unroll
        for (int r = 0; r < 16; ++r) Hm[r * 512 + col] = gelu_exact(acc[r] + bv);
    }
    __syncthreads();
    // Hm @ Wout + bout
    int col = tid & 127, hf = tid >> 7;
    float acc2[8];
#pragma unroll
    for (int r = 0; r < 8; ++r) acc2[r] = 0.f;
    for (int k = 0; k < 512; ++k) {
        float wv = Wout[(size_t)k * 128 + col];
#pragma unroll
        for (int r = 0; r < 8; ++r) acc2[r] += Hm[(hf * 8 + r) * 512 + k] * wv;
    }
    __syncthreads();
    float bo = bout[col];
#pragma unroll
    for (int r = 0; r < 8; ++r) {
        int rr = hf * 8 + r;
        Hm[rr * 128 + col] = X[rr * 128 + col] + acc2[r] + bo;  // residual pre-LN
    }
    __syncthreads();
    // LN per row (wave per row), then mask_V
#pragma unroll
    for (int p = 0; p < 4; ++p) {
        int r = p * 4 + w;
        float u0 = Hm[r * 128 + lane], u1 = Hm[r * 128 + lane + 64];
        float s = wred(u0 + u1);
        float mu = s * (1.0f / 128.0f);
        float d0 = u0 - mu, d1 = u1 - mu;
        float vs = wred(d0 * d0 + d1 * d1);
        float rs = rsqrtf(vs * (1.0f / 128.0f) + 1e-5f);
        float mv = maskV[n0 + r];
        hVout[(size_t)(n0 + r) * 128 + lane] = mv * (d0 * rs * g2[lane] + be2[lane]);
        hVout[(size_t)(n0 + r) * 128 + lane + 64] = mv * (d1 * rs * g2[lane + 64] + be2[lane + 64]);
    }
}

// ---------------- edge update MLP + residual + LN3 ---------------------------
__global__ __launch_bounds__(256) void edge_upd_kernel(
    const float* __restrict__ hE, const int* __restrict__ Eidx,
    const short8* __restrict__ W11bp, const short8* __restrict__ W12p,
    const short8* __restrict__ W13p, const float* __restrict__ b12,
    const float* __restrict__ b13, const float* __restrict__ Ysg,
    const float* __restrict__ Yng, const float* __restrict__ g3,
    const float* __restrict__ be3, float* __restrict__ hEout) {
    const int node = blockIdx.x;
    const int bb = node >> 11;
    const int tid = threadIdx.x;
    const int lane = tid & 63, w = tid >> 6;

    __shared__ __align__(16) short A_sw[48 * 128];
    __shared__ float Yg[48 * 132];
    __shared__ float Eres[48 * 132];
    __shared__ float Ysh[128];

    const float* Eb = hE + (size_t)node * 6144;
#pragma unroll
    for (int i = 0; i < 3; ++i) {
        int e = tid + i * 256;
        int r = e >> 4, c0 = (e & 15) * 8;
        float4 f0 = *(const float4*)(Eb + r * 128 + c0);
        float4 f1 = *(const float4*)(Eb + r * 128 + c0 + 4);
        short8 v;
        v[0] = f2bf(f0.x); v[1] = f2bf(f0.y); v[2] = f2bf(f0.z); v[3] = f2bf(f0.w);
        v[4] = f2bf(f1.x); v[5] = f2bf(f1.y); v[6] = f2bf(f1.z); v[7] = f2bf(f1.w);
        *(short8*)((char*)A_sw + r * 256 + ((c0 * 2) ^ ((r & 7) << 4))) = v;
        *(float4*)(&Eres[r * 132 + c0]) = f0;
        *(float4*)(&Eres[r * 132 + c0 + 4]) = f1;
    }
    if (tid < 128) Ysh[tid] = Ysg[(size_t)node * 128 + tid];
#pragma unroll 4
    for (int i = 0; i < 24; ++i) {
        int e = tid + i * 256;
        int r = e >> 7, c = e & 127;
        int idx = Eidx[node * 48 + r];
        Yg[r * 132 + c] = Yng[((size_t)bb * 2048 + idx) * 128 + c];
    }
    __syncthreads();

    f32x4 acc[3][2];
    gemm48(A_sw, W11bp, w, lane, acc);
    __syncthreads();
#pragma unroll
    for (int mt = 0; mt < 3; ++mt)
#pragma unroll
        for (int n2 = 0; n2 < 2; ++n2) {
            int col = (w * 2 + n2) * 16 + (lane & 15);
#pragma unroll
            for (int i = 0; i < 4; ++i) {
                int row = mt * 16 + (lane >> 4) * 4 + i;
                float v = acc[mt][n2][i] + Ysh[col] + Yg[row * 132 + col];
                v = gelu_exact(v);
                *(short*)((char*)A_sw + row * 256 + ((col * 2) ^ ((row & 7) << 4))) = f2bf(v);
            }
        }
    __syncthreads();
    gemm48(A_sw, W12p, w, lane, acc);
    __syncthreads();
#pragma unroll
    for (int mt = 0; mt < 3; ++mt)
#pragma unroll
        for (int n2 = 0; n2 < 2; ++n2) {
            int col = (w * 2 + n2) * 16 + (lane & 15);
            float bv = b12[col];
#pragma unroll
            for (int i = 0; i < 4; ++i) {
                int row = mt * 16 + (lane >> 4) * 4 + i;
                float v = gelu_exact(acc[mt][n2][i] + bv);
                *(short*)((char*)A_sw + row * 256 + ((col * 2) ^ ((row & 7) << 4))) = f2bf(v);
            }
        }
    __syncthreads();
    gemm48(A_sw, W13p, w, lane, acc);
#pragma unroll
    for (int mt = 0; mt < 3; ++mt)
#pragma unroll
        for (int n2 = 0; n2 < 2; ++n2) {
            int col = (w * 2 + n2) * 16 + (lane & 15);
            float bv = b13[col];
#pragma unroll
            for (int i = 0; i < 4; ++i) {
                int row = mt * 16 + (lane >> 4) * 4 + i;
                Yg[row * 132 + col] = acc[mt][n2][i] + bv + Eres[row * 132 + col];
            }
        }
    __syncthreads();

    // LN per edge row, wave per row
    float* outb = hEout + (size_t)node * 6144;
#pragma unroll
    for (int p = 0; p < 12; ++p) {
        int r = p * 4 + w;
        float u0 = Yg[r * 132 + lane], u1 = Yg[r * 132 + lane + 64];
        float s = wred(u0 + u1);
        float mu = s * (1.0f / 128.0f);
        float d0 = u0 - mu, d1 = u1 - mu;
        float vs = wred(d0 * d0 + d1 * d1);
        float rs = rsqrtf(vs * (1.0f / 128.0f) + 1e-5f);
        outb[r * 128 + lane] = d0 * rs * g3[lane] + be3[lane];
        outb[r * 128 + lane + 64] = d1 * rs * g3[lane + 64] + be3[lane + 64];
    }
}

extern "C" void kernel_launch(void* const* d_in, const int* in_sizes, int n_in,
                              void* d_out, int out_size, void* d_ws, size_t ws_size,
                              hipStream_t stream) {
    const float* hV      = (const float*)d_in[0];
    const float* hE      = (const float*)d_in[1];
    const int*   Eidx    = (const int*)d_in[2];
    const float* maskV   = (const float*)d_in[3];
    const float* maskAtt = (const float*)d_in[4];
    const float* W1  = (const float*)d_in[5];
    const float* b1  = (const float*)d_in[6];
    const float* W2  = (const float*)d_in[7];
    const float* b2  = (const float*)d_in[8];
    const float* W3  = (const float*)d_in[9];
    const float* b3  = (const float*)d_in[10];
    const float* W11 = (const float*)d_in[11];
    const float* b11 = (const float*)d_in[12];
    const float* W12 = (const float*)d_in[13];
    const float* b12 = (const float*)d_in[14];
    const float* W13 = (const float*)d_in[15];
    const float* b13 = (const float*)d_in[16];
    const float* Win = (const float*)d_in[17];
    const float* binp= (const float*)d_in[18];
    const float* Wout= (const float*)d_in[19];
    const float* bout= (const float*)d_in[20];
    const float* g1  = (const float*)d_in[21];
    const float* be1 = (const float*)d_in[22];
    const float* g2  = (const float*)d_in[23];
    const float* be2 = (const float*)d_in[24];
    const float* g3  = (const float*)d_in[25];
    const float* be3 = (const float*)d_in[26];

    char* ws = (char*)d_ws;
    short* W1bp  = (short*)(ws);
    short* W2p   = (short*)(ws + 32768);
    short* W3p   = (short*)(ws + 65536);
    short* W11bp = (short*)(ws + 98304);
    short* W12p  = (short*)(ws + 131072);
    short* W13p  = (short*)(ws + 163840);
    float* Ys    = (float*)(ws + 262144);
    float* Yn    = (float*)(ws + 262144 + 2097152);
    float* hv1   = (float*)(ws + 262144 + 2 * 2097152);

    float* hVout = (float*)d_out;                   // [2*2048*128]
    float* hEout = hVout + 2 * 2048 * 128;          // [2*2048*48*128]

    const int NNODE = 2 * 2048;

    // pack the six 128x128 bf16 weight matrices (middle block of W1/W11, W2, W3, ...)
    pack_w_kernel<<<8, 256, 0, stream>>>(W1 + 128 * 128, W1bp, 4, 128);
    pack_w_kernel<<<8, 256, 0, stream>>>(W2, W2p, 4, 128);
    pack_w_kernel<<<8, 256, 0, stream>>>(W3, W3p, 4, 128);
    pack_w_kernel<<<8, 256, 0, stream>>>(W11 + 128 * 128, W11bp, 4, 128);
    pack_w_kernel<<<8, 256, 0, stream>>>(W12, W12p, 4, 128);
    pack_w_kernel<<<8, 256, 0, stream>>>(W13, W13p, 4, 128);

    // node precompute: Ys = hV@W1[0:128]+b1, Yn = hV@W1[256:384]
    node_pre_kernel<<<NNODE / 8, 256, 0, stream>>>(hV, W1, b1, Ys, Yn);

    // node message MLP + masked mean + LN1 -> hv1
    node_msg_kernel<<<NNODE, 256, 0, stream>>>(hV, hE, Eidx, maskAtt,
        (const short8*)W1bp, (const short8*)W2p, (const short8*)W3p,
        b2, b3, Ys, Yn, g1, be1, hv1);

    // FFN + LN2 + mask_V -> hVout
    ffn_kernel<<<NNODE / 16, 256, 0, stream>>>(hv1, Win, binp, Wout, bout, g2, be2,
                                               maskV, hVout);

    // edge precompute on updated nodes: Ys = hVout@W11[0:128]+b11, Yn = hVout@W11[256:384]
    node_pre_kernel<<<NNODE / 8, 256, 0, stream>>>(hVout, W11, b11, Ys, Yn);

    // edge update MLP + residual + LN3 -> hEout
    edge_upd_kernel<<<NNODE, 256, 0, stream>>>(hE, Eidx,
        (const short8*)W11bp, (const short8*)W12p, (const short8*)W13p,
        b12, b13, Ys, Yn, g3, be3, hEout);
}

// Round 3
// 204.263 us; speedup vs baseline: 1.4188x; 1.4188x over previous
//
#include <hip/hip_runtime.h>
#include <hip/hip_bf16.h>

typedef __attribute__((ext_vector_type(8))) short short8;
typedef __attribute__((ext_vector_type(4))) float f32x4;

__device__ inline short f2bf(float f) {
    unsigned u = __builtin_bit_cast(unsigned, f);
    u += 0x7fffu + ((u >> 16) & 1u);
    return (short)(u >> 16);
}
__device__ inline float bf2f(short s) {
    return __builtin_bit_cast(float, ((unsigned)(unsigned short)s) << 16);
}
// tanh-form gelu: ~8 VALU ops, max abs err ~3e-3 vs exact
__device__ inline float gelu_fast(float x) {
    float z = x * (1.0f + 0.044715f * x * x);
    float e = __expf(1.5957691216f * z);            // exp(2*0.79788456*z)
    return x - x * __builtin_amdgcn_rcpf(e + 1.0f); // x*(1 - 1/(e+1)) ; inf/0 safe
}
__device__ inline float wred(float s) {
#pragma unroll
    for (int o = 32; o; o >>= 1) s += __shfl_xor(s, o, 64);
    return s;
}

// ---- pack all six 128x128 fp32 weights into bf16 MFMA-B fragment order -----
// B-frag (16x16x32): lane l holds B[k=(l>>4)*8+j][n=l&15]; slot (nt*4+kt)*64+lane.
__global__ void pack_all_kernel(const float* __restrict__ W1, const float* __restrict__ W2,
                                const float* __restrict__ W3, const float* __restrict__ W11,
                                const float* __restrict__ W12, const float* __restrict__ W13,
                                short* __restrict__ out) {
    int which = blockIdx.x >> 3;
    const float* Ws[6] = {W1 + 128 * 128, W2, W3, W11 + 128 * 128, W12, W13};
    const float* W = Ws[which];
    int i = (blockIdx.x & 7) * 256 + threadIdx.x;   // 0..2047 fragment slots
    int lane = i & 63, tile = i >> 6;
    int kt = tile & 3, nt = tile >> 2;
    int n = nt * 16 + (lane & 15);
    int k0 = kt * 32 + (lane >> 4) * 8;
    short8 v;
#pragma unroll
    for (int j = 0; j < 8; ++j) v[j] = f2bf(W[(size_t)(k0 + j) * 128 + n]);
    *(short8*)(out + (size_t)which * 16384 + (size_t)i * 8) = v;
}

// ---- per-node precompute: Ys = x@W[0:128]+b (fp32), Yn = x@W[256:384] (bf16) -
__global__ __launch_bounds__(256) void node_pre_kernel(
    const float* __restrict__ hV, const float* __restrict__ W,
    const float* __restrict__ bias, float* __restrict__ Ys, short* __restrict__ Yn) {
    int n0 = blockIdx.x * 8;
    int tid = threadIdx.x;
    int col = tid & 127;
    int half = tid >> 7;
    __shared__ float X[8 * 128];
    for (int i = tid; i < 1024; i += 256) X[i] = hV[(size_t)n0 * 128 + i];
    __syncthreads();
    const float* Wp = W + (half ? 256 * 128 : 0);
    float acc[8];
#pragma unroll
    for (int r = 0; r < 8; ++r) acc[r] = 0.f;
    for (int k = 0; k < 128; ++k) {
        float wv = Wp[(size_t)k * 128 + col];
#pragma unroll
        for (int r = 0; r < 8; ++r) acc[r] += X[r * 128 + k] * wv;
    }
    if (half) {
#pragma unroll
        for (int r = 0; r < 8; ++r) Yn[(size_t)(n0 + r) * 128 + col] = f2bf(acc[r]);
    } else {
        float bb = bias[col];
#pragma unroll
        for (int r = 0; r < 8; ++r) Ys[(size_t)(n0 + r) * 128 + col] = acc[r] + bb;
    }
}

// ---- 48x128 @ 128x128 MFMA GEMM; A bf16 XOR-swizzled in LDS ----------------
__device__ inline void gemm48(const short* A_sw, const short8* __restrict__ Bp,
                              int w, int lane, f32x4 acc[3][2]) {
#pragma unroll
    for (int mt = 0; mt < 3; ++mt)
#pragma unroll
        for (int n2 = 0; n2 < 2; ++n2) acc[mt][n2] = (f32x4){0.f, 0.f, 0.f, 0.f};
#pragma unroll
    for (int kt = 0; kt < 4; ++kt) {
        short8 a[3];
        int kb = (kt * 32 + (lane >> 4) * 8) * 2;
#pragma unroll
        for (int mt = 0; mt < 3; ++mt) {
            int row = mt * 16 + (lane & 15);
            a[mt] = *(const short8*)((const char*)A_sw + row * 256 + (kb ^ ((row & 7) << 4)));
        }
#pragma unroll
        for (int n2 = 0; n2 < 2; ++n2) {
            short8 bf = Bp[((w * 2 + n2) * 4 + kt) * 64 + lane];
#pragma unroll
            for (int mt = 0; mt < 3; ++mt)
                acc[mt][n2] = __builtin_amdgcn_mfma_f32_16x16x32_bf16(a[mt], bf, acc[mt][n2], 0, 0, 0);
        }
    }
}

// stage one node's h_E tile (fp32 global) into bf16 swizzled LDS
__device__ inline void stage_hE(const float* __restrict__ Eb, short* A_sw, int tid,
                                short* Eres /*optional bf16 copy, stride 136*/) {
#pragma unroll
    for (int i = 0; i < 3; ++i) {
        int e = tid + i * 256;
        int r = e >> 4, c0 = (e & 15) * 8;
        float4 f0 = *(const float4*)(Eb + r * 128 + c0);
        float4 f1 = *(const float4*)(Eb + r * 128 + c0 + 4);
        short8 v;
        v[0] = f2bf(f0.x); v[1] = f2bf(f0.y); v[2] = f2bf(f0.z); v[3] = f2bf(f0.w);
        v[4] = f2bf(f1.x); v[5] = f2bf(f1.y); v[6] = f2bf(f1.z); v[7] = f2bf(f1.w);
        *(short8*)((char*)A_sw + r * 256 + ((c0 * 2) ^ ((r & 7) << 4))) = v;
        if (Eres) *(short8*)(Eres + r * 136 + c0) = v;
    }
}

// gather 48 rows of Yn[E_idx] (bf16, 128 cols) into LDS with stride 136
__device__ inline void gather_Yn(const short* __restrict__ Yng, const int* __restrict__ Eidx,
                                 int node, int bb, int tid, short* Ygb) {
    if (tid < 192) {
        int r = tid >> 2, q = tid & 3;
        int idx = Eidx[node * 48 + r];
        const short8* src = (const short8*)(Yng + ((size_t)bb * 2048 + idx) * 128 + q * 32);
        short8* dst = (short8*)(Ygb + r * 136 + q * 32);
        dst[0] = src[0];
        dst[1] = src[1];
        dst[2] = src[2];
        dst[3] = src[3];
    }
}

// ---- node message MLP + masked mean + LN1 ----------------------------------
__global__ __launch_bounds__(256) void node_msg_kernel(
    const float* __restrict__ hV, const float* __restrict__ hE,
    const int* __restrict__ Eidx, const float* __restrict__ maskAtt,
    const short8* __restrict__ W1bp, const short8* __restrict__ W2p,
    const short8* __restrict__ W3p, const float* __restrict__ b2,
    const float* __restrict__ b3, const float* __restrict__ Ysg,
    const short* __restrict__ Yng, const float* __restrict__ g1,
    const float* __restrict__ be1, float* __restrict__ hv1out) {
    const int node = blockIdx.x;
    const int bb = node >> 11;
    const int tid = threadIdx.x;
    const int lane = tid & 63, w = tid >> 6;

    __shared__ __align__(16) short A_sw[48 * 128];   // 12288 B
    __shared__ __align__(16) short Ygb[48 * 136];    // 13056 B (gathered Yn, bf16)
    __shared__ float Ysh[128];
    __shared__ float mask_s[48];
    __shared__ float red[8];

    stage_hE(hE + (size_t)node * 6144, A_sw, tid, nullptr);
    if (tid < 128) Ysh[tid] = Ysg[(size_t)node * 128 + tid];
    if (tid >= 128 && tid < 176) mask_s[tid - 128] = maskAtt[node * 48 + tid - 128];
    gather_Yn(Yng, Eidx, node, bb, tid, Ygb);
    __syncthreads();

    f32x4 acc[3][2];
    // layer 1: h_E@W1b + Ys + Yn[idx], gelu
    gemm48(A_sw, W1bp, w, lane, acc);
    __syncthreads();
#pragma unroll
    for (int mt = 0; mt < 3; ++mt)
#pragma unroll
        for (int n2 = 0; n2 < 2; ++n2) {
            int col = (w * 2 + n2) * 16 + (lane & 15);
            float ysv = Ysh[col];
#pragma unroll
            for (int i = 0; i < 4; ++i) {
                int row = mt * 16 + (lane >> 4) * 4 + i;
                float v = acc[mt][n2][i] + ysv + bf2f(Ygb[row * 136 + col]);
                v = gelu_fast(v);
                *(short*)((char*)A_sw + row * 256 + ((col * 2) ^ ((row & 7) << 4))) = f2bf(v);
            }
        }
    __syncthreads();
    // layer 2
    gemm48(A_sw, W2p, w, lane, acc);
    __syncthreads();
#pragma unroll
    for (int mt = 0; mt < 3; ++mt)
#pragma unroll
        for (int n2 = 0; n2 < 2; ++n2) {
            int col = (w * 2 + n2) * 16 + (lane & 15);
            float bv = b2[col];
#pragma unroll
            for (int i = 0; i < 4; ++i) {
                int row = mt * 16 + (lane >> 4) * 4 + i;
                float v = gelu_fast(acc[mt][n2][i] + bv);
                *(short*)((char*)A_sw + row * 256 + ((col * 2) ^ ((row & 7) << 4))) = f2bf(v);
            }
        }
    __syncthreads();
    // layer 3 + masked column-sum straight from accumulators
    gemm48(A_sw, W3p, w, lane, acc);
    float u[2];
#pragma unroll
    for (int n2 = 0; n2 < 2; ++n2) {
        int col = (w * 2 + n2) * 16 + (lane & 15);
        float b3c = b3[col];
        float s = 0.f;
#pragma unroll
        for (int mt = 0; mt < 3; ++mt)
#pragma unroll
            for (int i = 0; i < 4; ++i) {
                int row = mt * 16 + (lane >> 4) * 4 + i;
                s += (acc[mt][n2][i] + b3c) * mask_s[row];
            }
        s += __shfl_xor(s, 16, 64);
        s += __shfl_xor(s, 32, 64);   // now total over all 48 rows, replicated
        u[n2] = hV[(size_t)node * 128 + col] + s * (1.0f / 30.0f);
    }
    // LN1 over 128 cols (each wave owns 32 cols, values replicated 4x in-wave)
    float ps = wred(u[0] + u[1]) * 0.25f;
    float pq = wred(u[0] * u[0] + u[1] * u[1]) * 0.25f;
    if (lane == 0) { red[w] = ps; red[4 + w] = pq; }
    __syncthreads();
    float S = red[0] + red[1] + red[2] + red[3];
    float Q = red[4] + red[5] + red[6] + red[7];
    float mu = S * (1.0f / 128.0f);
    float var = Q * (1.0f / 128.0f) - mu * mu;
    float rs = rsqrtf(var + 1e-5f);
    if ((lane >> 4) == 0) {
#pragma unroll
        for (int n2 = 0; n2 < 2; ++n2) {
            int col = (w * 2 + n2) * 16 + (lane & 15);
            hv1out[(size_t)node * 128 + col] = (u[n2] - mu) * rs * g1[col] + be1[col];
        }
    }
}

// ---- position-wise FFN + LN2 + mask_V ---------------------------------------
__global__ __launch_bounds__(256) void ffn_kernel(
    const float* __restrict__ hv1, const float* __restrict__ Win,
    const float* __restrict__ binp, const float* __restrict__ Wout,
    const float* __restrict__ bout, const float* __restrict__ g2,
    const float* __restrict__ be2, const float* __restrict__ maskV,
    float* __restrict__ hVout) {
    int n0 = blockIdx.x * 16;
    int tid = threadIdx.x, lane = tid & 63, w = tid >> 6;
    __shared__ float X[16 * 128];
    __shared__ float Hm[16 * 512];
    for (int i = tid; i < 2048; i += 256) X[i] = hv1[(size_t)n0 * 128 + i];
    __syncthreads();
#pragma unroll
    for (int half = 0; half < 2; ++half) {
        int col = half * 256 + tid;
        float acc[16];
#pragma unroll
        for (int r = 0; r < 16; ++r) acc[r] = 0.f;
        for (int k = 0; k < 128; ++k) {
            float wv = Win[(size_t)k * 512 + col];
#pragma unroll
            for (int r = 0; r < 16; ++r) acc[r] += X[r * 128 + k] * wv;
        }
        float bv = binp[col];
#pragma unroll
        for (int r = 0; r < 16; ++r) Hm[r * 512 + col] = gelu_fast(acc[r] + bv);
    }
    __syncthreads();
    int col = tid & 127, hf = tid >> 7;
    float acc2[8];
#pragma unroll
    for (int r = 0; r < 8; ++r) acc2[r] = 0.f;
    for (int k = 0; k < 512; ++k) {
        float wv = Wout[(size_t)k * 128 + col];
#pragma unroll
        for (int r = 0; r < 8; ++r) acc2[r] += Hm[(hf * 8 + r) * 512 + k] * wv;
    }
    __syncthreads();
    float bo = bout[col];
#pragma unroll
    for (int r = 0; r < 8; ++r) {
        int rr = hf * 8 + r;
        Hm[rr * 128 + col] = X[rr * 128 + col] + acc2[r] + bo;  // residual pre-LN
    }
    __syncthreads();
#pragma unroll
    for (int p = 0; p < 4; ++p) {
        int r = p * 4 + w;
        float u0 = Hm[r * 128 + lane], u1 = Hm[r * 128 + lane + 64];
        float s = wred(u0 + u1);
        float q = wred(u0 * u0 + u1 * u1);
        float mu = s * (1.0f / 128.0f);
        float var = q * (1.0f / 128.0f) - mu * mu;
        float rs = rsqrtf(var + 1e-5f);
        float mv = maskV[n0 + r];
        hVout[(size_t)(n0 + r) * 128 + lane] = mv * ((u0 - mu) * rs * g2[lane] + be2[lane]);
        hVout[(size_t)(n0 + r) * 128 + lane + 64] = mv * ((u1 - mu) * rs * g2[lane + 64] + be2[lane + 64]);
    }
}

// ---- edge update MLP + residual + LN3 ---------------------------------------
__global__ __launch_bounds__(256) void edge_upd_kernel(
    const float* __restrict__ hE, const int* __restrict__ Eidx,
    const short8* __restrict__ W11bp, const short8* __restrict__ W12p,
    const short8* __restrict__ W13p, const float* __restrict__ b12,
    const float* __restrict__ b13, const float* __restrict__ Ysg,
    const short* __restrict__ Yng, const float* __restrict__ g3,
    const float* __restrict__ be3, float* __restrict__ hEout) {
    const int node = blockIdx.x;
    const int bb = node >> 11;
    const int tid = threadIdx.x;
    const int lane = tid & 63, w = tid >> 6;

    __shared__ __align__(16) short A_sw[48 * 128];   // 12288 B
    __shared__ __align__(16) short Ygb[48 * 136];    // gather, then pre-LN stash
    __shared__ __align__(16) short Eres[48 * 136];   // bf16 residual copy
    __shared__ float Ysh[128];

    stage_hE(hE + (size_t)node * 6144, A_sw, tid, Eres);
    if (tid < 128) Ysh[tid] = Ysg[(size_t)node * 128 + tid];
    gather_Yn(Yng, Eidx, node, bb, tid, Ygb);
    __syncthreads();

    f32x4 acc[3][2];
    gemm48(A_sw, W11bp, w, lane, acc);
    __syncthreads();
#pragma unroll
    for (int mt = 0; mt < 3; ++mt)
#pragma unroll
        for (int n2 = 0; n2 < 2; ++n2) {
            int col = (w * 2 + n2) * 16 + (lane & 15);
            float ysv = Ysh[col];
#pragma unroll
            for (int i = 0; i < 4; ++i) {
                int row = mt * 16 + (lane >> 4) * 4 + i;
                float v = acc[mt][n2][i] + ysv + bf2f(Ygb[row * 136 + col]);
                v = gelu_fast(v);
                *(short*)((char*)A_sw + row * 256 + ((col * 2) ^ ((row & 7) << 4))) = f2bf(v);
            }
        }
    __syncthreads();
    gemm48(A_sw, W12p, w, lane, acc);
    __syncthreads();
#pragma unroll
    for (int mt = 0; mt < 3; ++mt)
#pragma unroll
        for (int n2 = 0; n2 < 2; ++n2) {
            int col = (w * 2 + n2) * 16 + (lane & 15);
            float bv = b12[col];
#pragma unroll
            for (int i = 0; i < 4; ++i) {
                int row = mt * 16 + (lane >> 4) * 4 + i;
                float v = gelu_fast(acc[mt][n2][i] + bv);
                *(short*)((char*)A_sw + row * 256 + ((col * 2) ^ ((row & 7) << 4))) = f2bf(v);
            }
        }
    __syncthreads();
    gemm48(A_sw, W13p, w, lane, acc);
    // pre-LN value = msg + b13 + residual, stash bf16 into Ygb (gather is dead)
#pragma unroll
    for (int mt = 0; mt < 3; ++mt)
#pragma unroll
        for (int n2 = 0; n2 < 2; ++n2) {
            int col = (w * 2 + n2) * 16 + (lane & 15);
            float bv = b13[col];
#pragma unroll
            for (int i = 0; i < 4; ++i) {
                int row = mt * 16 + (lane >> 4) * 4 + i;
                float v = acc[mt][n2][i] + bv + bf2f(Eres[row * 136 + col]);
                Ygb[row * 136 + col] = f2bf(v);
            }
        }
    __syncthreads();

    // LN per edge row (wave per row), coalesced output
    float* outb = hEout + (size_t)node * 6144;
    float gl0 = g3[lane], gl1 = g3[lane + 64];
    float bl0 = be3[lane], bl1 = be3[lane + 64];
#pragma unroll
    for (int p = 0; p < 12; ++p) {
        int r = p * 4 + w;
        float u0 = bf2f(Ygb[r * 136 + lane]);
        float u1 = bf2f(Ygb[r * 136 + lane + 64]);
        float s = wred(u0 + u1);
        float q = wred(u0 * u0 + u1 * u1);
        float mu = s * (1.0f / 128.0f);
        float var = q * (1.0f / 128.0f) - mu * mu;
        float rs = rsqrtf(var + 1e-5f);
        outb[r * 128 + lane] = (u0 - mu) * rs * gl0 + bl0;
        outb[r * 128 + lane + 64] = (u1 - mu) * rs * gl1 + bl1;
    }
}

extern "C" void kernel_launch(void* const* d_in, const int* in_sizes, int n_in,
                              void* d_out, int out_size, void* d_ws, size_t ws_size,
                              hipStream_t stream) {
    const float* hV      = (const float*)d_in[0];
    const float* hE      = (const float*)d_in[1];
    const int*   Eidx    = (const int*)d_in[2];
    const float* maskV   = (const float*)d_in[3];
    const float* maskAtt = (const float*)d_in[4];
    const float* W1  = (const float*)d_in[5];
    const float* b1  = (const float*)d_in[6];
    const float* W2  = (const float*)d_in[7];
    const float* b2  = (const float*)d_in[8];
    const float* W3  = (const float*)d_in[9];
    const float* b3  = (const float*)d_in[10];
    const float* W11 = (const float*)d_in[11];
    const float* b11 = (const float*)d_in[12];
    const float* W12 = (const float*)d_in[13];
    const float* b12 = (const float*)d_in[14];
    const float* W13 = (const float*)d_in[15];
    const float* b13 = (const float*)d_in[16];
    const float* Win = (const float*)d_in[17];
    const float* binp= (const float*)d_in[18];
    const float* Wout= (const float*)d_in[19];
    const float* bout= (const float*)d_in[20];
    const float* g1  = (const float*)d_in[21];
    const float* be1 = (const float*)d_in[22];
    const float* g2  = (const float*)d_in[23];
    const float* be2 = (const float*)d_in[24];
    const float* g3  = (const float*)d_in[25];
    const float* be3 = (const float*)d_in[26];

    char* ws = (char*)d_ws;
    short* Wpk  = (short*)ws;                        // 6 * 32768 B packed weights
    float* Ys   = (float*)(ws + 262144);             // 2 MB fp32
    short* Yn   = (short*)(ws + 262144 + 2097152);   // 1 MB bf16
    float* hv1  = (float*)(ws + 262144 + 2097152 + 1048576); // 2 MB fp32

    float* hVout = (float*)d_out;
    float* hEout = hVout + 2 * 2048 * 128;

    const int NNODE = 2 * 2048;

    pack_all_kernel<<<48, 256, 0, stream>>>(W1, W2, W3, W11, W12, W13, Wpk);

    node_pre_kernel<<<NNODE / 8, 256, 0, stream>>>(hV, W1, b1, Ys, Yn);

    node_msg_kernel<<<NNODE, 256, 0, stream>>>(hV, hE, Eidx, maskAtt,
        (const short8*)(Wpk), (const short8*)(Wpk + 16384), (const short8*)(Wpk + 32768),
        b2, b3, Ys, Yn, g1, be1, hv1);

    ffn_kernel<<<NNODE / 16, 256, 0, stream>>>(hv1, Win, binp, Wout, bout, g2, be2,
                                               maskV, hVout);

    node_pre_kernel<<<NNODE / 8, 256, 0, stream>>>(hVout, W11, b11, Ys, Yn);

    edge_upd_kernel<<<NNODE, 256, 0, stream>>>(hE, Eidx,
        (const short8*)(Wpk + 49152), (const short8*)(Wpk + 65536), (const short8*)(Wpk + 81920),
        b12, b13, Ys, Yn, g3, be3, hEout);
}

// Round 4
// 141.679 us; speedup vs baseline: 2.0456x; 1.4417x over previous
//
#include <hip/hip_runtime.h>
#include <hip/hip_bf16.h>

typedef __attribute__((ext_vector_type(8))) short short8;
typedef __attribute__((ext_vector_type(4))) float f32x4;

__device__ inline short f2bf(float f) {
    unsigned u = __builtin_bit_cast(unsigned, f);
    u += 0x7fffu + ((u >> 16) & 1u);
    return (short)(u >> 16);
}
__device__ inline float bf2f(short s) {
    return __builtin_bit_cast(float, ((unsigned)(unsigned short)s) << 16);
}
// tanh-form gelu: ~8 VALU ops, max abs err ~3e-3 vs exact
__device__ inline float gelu_fast(float x) {
    float z = x * (1.0f + 0.044715f * x * x);
    float e = __expf(1.5957691216f * z);            // exp(2*0.79788456*z)
    return x - x * __builtin_amdgcn_rcpf(e + 1.0f); // x*(1 - 1/(e+1))
}
__device__ inline float wred(float s) {
#pragma unroll
    for (int o = 32; o; o >>= 1) s += __shfl_xor(s, o, 64);
    return s;
}

// ---- pack all weights into bf16 MFMA-B fragment order -----------------------
// B-frag (16x16x32): lane l holds B[k=(l>>4)*8+j][n=l&15]; slot (nt*Kt+kt)*64+lane.
// blocks 0..79: ten 128x128 mats; 80..111: Win(128x512); 112..143: Wout(512x128)
__global__ void pack_all_kernel(const float* __restrict__ W1, const float* __restrict__ W2,
                                const float* __restrict__ W3, const float* __restrict__ W11,
                                const float* __restrict__ W12, const float* __restrict__ W13,
                                const float* __restrict__ Win, const float* __restrict__ Wout,
                                short* __restrict__ out) {
    int b = blockIdx.x;
    if (b < 80) {
        int which = b >> 3;
        const float* Ws[10] = {W1 + 128 * 128, W2, W3, W11 + 128 * 128, W12, W13,
                               W1, W1 + 256 * 128, W11, W11 + 256 * 128};
        const float* W = Ws[which];
        int i = (b & 7) * 256 + threadIdx.x;     // 0..2047
        int lane = i & 63, tile = i >> 6;
        int kt = tile & 3, nt = tile >> 2;
        int n = nt * 16 + (lane & 15);
        int k0 = kt * 32 + (lane >> 4) * 8;
        short8 v;
#pragma unroll
        for (int j = 0; j < 8; ++j) v[j] = f2bf(W[(size_t)(k0 + j) * 128 + n]);
        *(short8*)(out + (size_t)which * 16384 + (size_t)i * 8) = v;
    } else if (b < 112) {
        int i = (b - 80) * 256 + threadIdx.x;    // 0..8191
        int lane = i & 63, tile = i >> 6;
        int kt = tile & 3, nt = tile >> 2;       // nt 0..31
        int n = nt * 16 + (lane & 15);
        int k0 = kt * 32 + (lane >> 4) * 8;
        short8 v;
#pragma unroll
        for (int j = 0; j < 8; ++j) v[j] = f2bf(Win[(size_t)(k0 + j) * 512 + n]);
        *(short8*)(out + 163840 + (size_t)i * 8) = v;
    } else {
        int i = (b - 112) * 256 + threadIdx.x;   // 0..8191
        int lane = i & 63, tile = i >> 6;
        int kt = tile & 15, nt = tile >> 4;      // nt 0..7, kt 0..15
        int n = nt * 16 + (lane & 15);
        int k0 = kt * 32 + (lane >> 4) * 8;
        short8 v;
#pragma unroll
        for (int j = 0; j < 8; ++j) v[j] = f2bf(Wout[(size_t)(k0 + j) * 128 + n]);
        *(short8*)(out + 229376 + (size_t)i * 8) = v;
    }
}

// ---- node precompute via MFMA: Ys = x@Wself+b (f32), Yn = x@Wnbr (bf16) -----
// M=16 nodes/block, 4 waves: waves 0,1 -> Ys cols, waves 2,3 -> Yn cols.
__global__ __launch_bounds__(256) void node_pre_kernel(
    const float* __restrict__ hV, const short8* __restrict__ Bs,
    const short8* __restrict__ Bn, const float* __restrict__ bias,
    float* __restrict__ Ys, short* __restrict__ Yn) {
    int n0 = blockIdx.x * 16;
    int tid = threadIdx.x, lane = tid & 63, w = tid >> 6;
    __shared__ __align__(16) short A_sw[16 * 128];
    {
        int off = tid * 8;
        int r = off >> 7, c0 = off & 127;
        const float* src = hV + (size_t)n0 * 128 + off;
        float4 f0 = *(const float4*)(src);
        float4 f1 = *(const float4*)(src + 4);
        short8 v;
        v[0] = f2bf(f0.x); v[1] = f2bf(f0.y); v[2] = f2bf(f0.z); v[3] = f2bf(f0.w);
        v[4] = f2bf(f1.x); v[5] = f2bf(f1.y); v[6] = f2bf(f1.z); v[7] = f2bf(f1.w);
        *(short8*)((char*)A_sw + r * 256 + ((c0 * 2) ^ ((r & 7) << 4))) = v;
    }
    __syncthreads();
    const short8* Bp = (w < 2) ? Bs : Bn;
    f32x4 acc[4];
#pragma unroll
    for (int n2 = 0; n2 < 4; ++n2) acc[n2] = (f32x4){0.f, 0.f, 0.f, 0.f};
#pragma unroll
    for (int kt = 0; kt < 4; ++kt) {
        int row = lane & 15;
        int kb = (kt * 32 + (lane >> 4) * 8) * 2;
        short8 a = *(const short8*)((const char*)A_sw + row * 256 + (kb ^ ((row & 7) << 4)));
#pragma unroll
        for (int n2 = 0; n2 < 4; ++n2) {
            int ntl = (w & 1) * 4 + n2;
            short8 bf = Bp[(ntl * 4 + kt) * 64 + lane];
            acc[n2] = __builtin_amdgcn_mfma_f32_16x16x32_bf16(a, bf, acc[n2], 0, 0, 0);
        }
    }
    if (w < 2) {
#pragma unroll
        for (int n2 = 0; n2 < 4; ++n2) {
            int col = ((w & 1) * 4 + n2) * 16 + (lane & 15);
            float bv = bias[col];
#pragma unroll
            for (int i = 0; i < 4; ++i) {
                int row = (lane >> 4) * 4 + i;
                Ys[(size_t)(n0 + row) * 128 + col] = acc[n2][i] + bv;
            }
        }
    } else {
#pragma unroll
        for (int n2 = 0; n2 < 4; ++n2) {
            int col = ((w & 1) * 4 + n2) * 16 + (lane & 15);
#pragma unroll
            for (int i = 0; i < 4; ++i) {
                int row = (lane >> 4) * 4 + i;
                Yn[(size_t)(n0 + row) * 128 + col] = f2bf(acc[n2][i]);
            }
        }
    }
}

// ---- 48x128 @ 128x128 MFMA GEMM; A bf16 XOR-swizzled in LDS ----------------
__device__ inline void gemm48(const short* A_sw, const short8* __restrict__ Bp,
                              int w, int lane, f32x4 acc[3][2]) {
#pragma unroll
    for (int mt = 0; mt < 3; ++mt)
#pragma unroll
        for (int n2 = 0; n2 < 2; ++n2) acc[mt][n2] = (f32x4){0.f, 0.f, 0.f, 0.f};
#pragma unroll
    for (int kt = 0; kt < 4; ++kt) {
        short8 a[3];
        int kb = (kt * 32 + (lane >> 4) * 8) * 2;
#pragma unroll
        for (int mt = 0; mt < 3; ++mt) {
            int row = mt * 16 + (lane & 15);
            a[mt] = *(const short8*)((const char*)A_sw + row * 256 + (kb ^ ((row & 7) << 4)));
        }
#pragma unroll
        for (int n2 = 0; n2 < 2; ++n2) {
            short8 bf = Bp[((w * 2 + n2) * 4 + kt) * 64 + lane];
#pragma unroll
            for (int mt = 0; mt < 3; ++mt)
                acc[mt][n2] = __builtin_amdgcn_mfma_f32_16x16x32_bf16(a[mt], bf, acc[mt][n2], 0, 0, 0);
        }
    }
}

// stage one node's h_E tile (fp32 global) into bf16 swizzled LDS
__device__ inline void stage_hE(const float* __restrict__ Eb, short* A_sw, int tid,
                                short* Eres /*optional bf16 copy, stride 136*/) {
#pragma unroll
    for (int i = 0; i < 3; ++i) {
        int e = tid + i * 256;
        int r = e >> 4, c0 = (e & 15) * 8;
        float4 f0 = *(const float4*)(Eb + r * 128 + c0);
        float4 f1 = *(const float4*)(Eb + r * 128 + c0 + 4);
        short8 v;
        v[0] = f2bf(f0.x); v[1] = f2bf(f0.y); v[2] = f2bf(f0.z); v[3] = f2bf(f0.w);
        v[4] = f2bf(f1.x); v[5] = f2bf(f1.y); v[6] = f2bf(f1.z); v[7] = f2bf(f1.w);
        *(short8*)((char*)A_sw + r * 256 + ((c0 * 2) ^ ((r & 7) << 4))) = v;
        if (Eres) *(short8*)(Eres + r * 136 + c0) = v;
    }
}

// gather 48 rows of Yn[E_idx] (bf16, 128 cols) into LDS with stride 136
__device__ inline void gather_Yn(const short* __restrict__ Yng, const int* __restrict__ Eidx,
                                 int node, int bb, int tid, short* Ygb) {
    if (tid < 192) {
        int r = tid >> 2, q = tid & 3;
        int idx = Eidx[node * 48 + r];
        const short8* src = (const short8*)(Yng + ((size_t)bb * 2048 + idx) * 128 + q * 32);
        short8* dst = (short8*)(Ygb + r * 136 + q * 32);
        dst[0] = src[0];
        dst[1] = src[1];
        dst[2] = src[2];
        dst[3] = src[3];
    }
}

// ---- node message MLP + masked mean + LN1 ----------------------------------
__global__ __launch_bounds__(256) void node_msg_kernel(
    const float* __restrict__ hV, const float* __restrict__ hE,
    const int* __restrict__ Eidx, const float* __restrict__ maskAtt,
    const short8* __restrict__ W1bp, const short8* __restrict__ W2p,
    const short8* __restrict__ W3p, const float* __restrict__ b2,
    const float* __restrict__ b3, const float* __restrict__ Ysg,
    const short* __restrict__ Yng, const float* __restrict__ g1,
    const float* __restrict__ be1, float* __restrict__ hv1out) {
    const int node = blockIdx.x;
    const int bb = node >> 11;
    const int tid = threadIdx.x;
    const int lane = tid & 63, w = tid >> 6;

    __shared__ __align__(16) short A_sw[48 * 128];   // 12288 B
    __shared__ __align__(16) short Ygb[48 * 136];    // 13056 B (gathered Yn, bf16)
    __shared__ float Ysh[128];
    __shared__ float mask_s[48];
    __shared__ float red[8];

    stage_hE(hE + (size_t)node * 6144, A_sw, tid, nullptr);
    if (tid < 128) Ysh[tid] = Ysg[(size_t)node * 128 + tid];
    if (tid >= 128 && tid < 176) mask_s[tid - 128] = maskAtt[node * 48 + tid - 128];
    gather_Yn(Yng, Eidx, node, bb, tid, Ygb);
    __syncthreads();

    f32x4 acc[3][2];
    // layer 1: h_E@W1b + Ys + Yn[idx], gelu
    gemm48(A_sw, W1bp, w, lane, acc);
    __syncthreads();
#pragma unroll
    for (int mt = 0; mt < 3; ++mt)
#pragma unroll
        for (int n2 = 0; n2 < 2; ++n2) {
            int col = (w * 2 + n2) * 16 + (lane & 15);
            float ysv = Ysh[col];
#pragma unroll
            for (int i = 0; i < 4; ++i) {
                int row = mt * 16 + (lane >> 4) * 4 + i;
                float v = acc[mt][n2][i] + ysv + bf2f(Ygb[row * 136 + col]);
                v = gelu_fast(v);
                *(short*)((char*)A_sw + row * 256 + ((col * 2) ^ ((row & 7) << 4))) = f2bf(v);
            }
        }
    __syncthreads();
    // layer 2
    gemm48(A_sw, W2p, w, lane, acc);
    __syncthreads();
#pragma unroll
    for (int mt = 0; mt < 3; ++mt)
#pragma unroll
        for (int n2 = 0; n2 < 2; ++n2) {
            int col = (w * 2 + n2) * 16 + (lane & 15);
            float bv = b2[col];
#pragma unroll
            for (int i = 0; i < 4; ++i) {
                int row = mt * 16 + (lane >> 4) * 4 + i;
                float v = gelu_fast(acc[mt][n2][i] + bv);
                *(short*)((char*)A_sw + row * 256 + ((col * 2) ^ ((row & 7) << 4))) = f2bf(v);
            }
        }
    __syncthreads();
    // layer 3 + masked column-sum straight from accumulators
    gemm48(A_sw, W3p, w, lane, acc);
    float u[2];
#pragma unroll
    for (int n2 = 0; n2 < 2; ++n2) {
        int col = (w * 2 + n2) * 16 + (lane & 15);
        float b3c = b3[col];
        float s = 0.f;
#pragma unroll
        for (int mt = 0; mt < 3; ++mt)
#pragma unroll
            for (int i = 0; i < 4; ++i) {
                int row = mt * 16 + (lane >> 4) * 4 + i;
                s += (acc[mt][n2][i] + b3c) * mask_s[row];
            }
        s += __shfl_xor(s, 16, 64);
        s += __shfl_xor(s, 32, 64);   // now total over all 48 rows, replicated
        u[n2] = hV[(size_t)node * 128 + col] + s * (1.0f / 30.0f);
    }
    // LN1 over 128 cols (each wave owns 32 cols, values replicated 4x in-wave)
    float ps = wred(u[0] + u[1]) * 0.25f;
    float pq = wred(u[0] * u[0] + u[1] * u[1]) * 0.25f;
    if (lane == 0) { red[w] = ps; red[4 + w] = pq; }
    __syncthreads();
    float S = red[0] + red[1] + red[2] + red[3];
    float Q = red[4] + red[5] + red[6] + red[7];
    float mu = S * (1.0f / 128.0f);
    float var = Q * (1.0f / 128.0f) - mu * mu;
    float rs = rsqrtf(var + 1e-5f);
    if ((lane >> 4) == 0) {
#pragma unroll
        for (int n2 = 0; n2 < 2; ++n2) {
            int col = (w * 2 + n2) * 16 + (lane & 15);
            hv1out[(size_t)node * 128 + col] = (u[n2] - mu) * rs * g1[col] + be1[col];
        }
    }
}

// ---- FFN via MFMA: [16x128]@[128x512] gelu @[512x128] + residual + LN2 ------
__global__ __launch_bounds__(256) void ffn_kernel(
    const float* __restrict__ hv1, const short8* __restrict__ Winp,
    const float* __restrict__ binp, const short8* __restrict__ Woutp,
    const float* __restrict__ bout, const float* __restrict__ g2,
    const float* __restrict__ be2, const float* __restrict__ maskV,
    float* __restrict__ hVout) {
    int n0 = blockIdx.x * 16;
    int tid = threadIdx.x, lane = tid & 63, w = tid >> 6;
    __shared__ float X[16 * 128];                    // 8 KB fp32 (residual + pre-LN)
    __shared__ __align__(16) short A_sw[16 * 128];   // 4 KB bf16 swizzled
    __shared__ __align__(16) short H_sw[16 * 512];   // 16 KB bf16 swizzled

    // stage hv1 tile: coalesced, keep fp32 copy + bf16 swizzled A
    {
        int off = tid * 8;
        int r = off >> 7, c0 = off & 127;
        const float* src = hv1 + (size_t)n0 * 128 + off;
        float4 f0 = *(const float4*)(src);
        float4 f1 = *(const float4*)(src + 4);
        *(float4*)(&X[off]) = f0;
        *(float4*)(&X[off + 4]) = f1;
        short8 v;
        v[0] = f2bf(f0.x); v[1] = f2bf(f0.y); v[2] = f2bf(f0.z); v[3] = f2bf(f0.w);
        v[4] = f2bf(f1.x); v[5] = f2bf(f1.y); v[6] = f2bf(f1.z); v[7] = f2bf(f1.w);
        *(short8*)((char*)A_sw + r * 256 + ((c0 * 2) ^ ((r & 7) << 4))) = v;
    }
    __syncthreads();

    // GEMM1: each wave covers n-tiles w*8..w*8+7 of 32 (cols w*128..w*128+127)
    f32x4 acc1[8];
#pragma unroll
    for (int n2 = 0; n2 < 8; ++n2) acc1[n2] = (f32x4){0.f, 0.f, 0.f, 0.f};
#pragma unroll
    for (int kt = 0; kt < 4; ++kt) {
        int row = lane & 15;
        int kb = (kt * 32 + (lane >> 4) * 8) * 2;
        short8 a = *(const short8*)((const char*)A_sw + row * 256 + (kb ^ ((row & 7) << 4)));
#pragma unroll
        for (int n2 = 0; n2 < 8; ++n2) {
            short8 bf = Winp[((w * 8 + n2) * 4 + kt) * 64 + lane];
            acc1[n2] = __builtin_amdgcn_mfma_f32_16x16x32_bf16(a, bf, acc1[n2], 0, 0, 0);
        }
    }
    // gelu(.+bin) -> H_sw (row stride 1024 B, same XOR swizzle)
#pragma unroll
    for (int n2 = 0; n2 < 8; ++n2) {
        int col = (w * 8 + n2) * 16 + (lane & 15);
        float bv = binp[col];
#pragma unroll
        for (int i = 0; i < 4; ++i) {
            int row = (lane >> 4) * 4 + i;
            float v = gelu_fast(acc1[n2][i] + bv);
            *(short*)((char*)H_sw + row * 1024 + ((col * 2) ^ ((row & 7) << 4))) = f2bf(v);
        }
    }
    __syncthreads();

    // GEMM2: each wave covers n-tiles w*2, w*2+1 of 8 (cols w*32..w*32+31)
    f32x4 acc2[2];
    acc2[0] = (f32x4){0.f, 0.f, 0.f, 0.f};
    acc2[1] = (f32x4){0.f, 0.f, 0.f, 0.f};
#pragma unroll
    for (int kt = 0; kt < 16; ++kt) {
        int row = lane & 15;
        int kb = (kt * 32 + (lane >> 4) * 8) * 2;
        short8 a = *(const short8*)((const char*)H_sw + row * 1024 + (kb ^ ((row & 7) << 4)));
#pragma unroll
        for (int n2 = 0; n2 < 2; ++n2) {
            short8 bf = Woutp[((w * 2 + n2) * 16 + kt) * 64 + lane];
            acc2[n2] = __builtin_amdgcn_mfma_f32_16x16x32_bf16(a, bf, acc2[n2], 0, 0, 0);
        }
    }
    // residual into X (pre-LN value)
#pragma unroll
    for (int n2 = 0; n2 < 2; ++n2) {
        int col = (w * 2 + n2) * 16 + (lane & 15);
        float bo = bout[col];
#pragma unroll
        for (int i = 0; i < 4; ++i) {
            int row = (lane >> 4) * 4 + i;
            X[row * 128 + col] += acc2[n2][i] + bo;
        }
    }
    __syncthreads();

    // LN per row + mask_V (4 rows per wave)
#pragma unroll
    for (int p = 0; p < 4; ++p) {
        int r = p * 4 + w;
        float u0 = X[r * 128 + lane], u1 = X[r * 128 + lane + 64];
        float s = wred(u0 + u1);
        float q = wred(u0 * u0 + u1 * u1);
        float mu = s * (1.0f / 128.0f);
        float var = q * (1.0f / 128.0f) - mu * mu;
        float rs = rsqrtf(var + 1e-5f);
        float mv = maskV[n0 + r];
        hVout[(size_t)(n0 + r) * 128 + lane] = mv * ((u0 - mu) * rs * g2[lane] + be2[lane]);
        hVout[(size_t)(n0 + r) * 128 + lane + 64] = mv * ((u1 - mu) * rs * g2[lane + 64] + be2[lane + 64]);
    }
}

// ---- edge update MLP + residual + LN3 ---------------------------------------
__global__ __launch_bounds__(256) void edge_upd_kernel(
    const float* __restrict__ hE, const int* __restrict__ Eidx,
    const short8* __restrict__ W11bp, const short8* __restrict__ W12p,
    const short8* __restrict__ W13p, const float* __restrict__ b12,
    const float* __restrict__ b13, const float* __restrict__ Ysg,
    const short* __restrict__ Yng, const float* __restrict__ g3,
    const float* __restrict__ be3, float* __restrict__ hEout) {
    const int node = blockIdx.x;
    const int bb = node >> 11;
    const int tid = threadIdx.x;
    const int lane = tid & 63, w = tid >> 6;

    __shared__ __align__(16) short A_sw[48 * 128];   // 12288 B
    __shared__ __align__(16) short Ygb[48 * 136];    // gather, then pre-LN stash
    __shared__ __align__(16) short Eres[48 * 136];   // bf16 residual copy
    __shared__ float Ysh[128];

    stage_hE(hE + (size_t)node * 6144, A_sw, tid, Eres);
    if (tid < 128) Ysh[tid] = Ysg[(size_t)node * 128 + tid];
    gather_Yn(Yng, Eidx, node, bb, tid, Ygb);
    __syncthreads();

    f32x4 acc[3][2];
    gemm48(A_sw, W11bp, w, lane, acc);
    __syncthreads();
#pragma unroll
    for (int mt = 0; mt < 3; ++mt)
#pragma unroll
        for (int n2 = 0; n2 < 2; ++n2) {
            int col = (w * 2 + n2) * 16 + (lane & 15);
            float ysv = Ysh[col];
#pragma unroll
            for (int i = 0; i < 4; ++i) {
                int row = mt * 16 + (lane >> 4) * 4 + i;
                float v = acc[mt][n2][i] + ysv + bf2f(Ygb[row * 136 + col]);
                v = gelu_fast(v);
                *(short*)((char*)A_sw + row * 256 + ((col * 2) ^ ((row & 7) << 4))) = f2bf(v);
            }
        }
    __syncthreads();
    gemm48(A_sw, W12p, w, lane, acc);
    __syncthreads();
#pragma unroll
    for (int mt = 0; mt < 3; ++mt)
#pragma unroll
        for (int n2 = 0; n2 < 2; ++n2) {
            int col = (w * 2 + n2) * 16 + (lane & 15);
            float bv = b12[col];
#pragma unroll
            for (int i = 0; i < 4; ++i) {
                int row = mt * 16 + (lane >> 4) * 4 + i;
                float v = gelu_fast(acc[mt][n2][i] + bv);
                *(short*)((char*)A_sw + row * 256 + ((col * 2) ^ ((row & 7) << 4))) = f2bf(v);
            }
        }
    __syncthreads();
    gemm48(A_sw, W13p, w, lane, acc);
    // pre-LN value = msg + b13 + residual, stash bf16 into Ygb (gather is dead)
#pragma unroll
    for (int mt = 0; mt < 3; ++mt)
#pragma unroll
        for (int n2 = 0; n2 < 2; ++n2) {
            int col = (w * 2 + n2) * 16 + (lane & 15);
            float bv = b13[col];
#pragma unroll
            for (int i = 0; i < 4; ++i) {
                int row = mt * 16 + (lane >> 4) * 4 + i;
                float v = acc[mt][n2][i] + bv + bf2f(Eres[row * 136 + col]);
                Ygb[row * 136 + col] = f2bf(v);
            }
        }
    __syncthreads();

    // LN per edge row (wave per row), coalesced output
    float* outb = hEout + (size_t)node * 6144;
    float gl0 = g3[lane], gl1 = g3[lane + 64];
    float bl0 = be3[lane], bl1 = be3[lane + 64];
#pragma unroll
    for (int p = 0; p < 12; ++p) {
        int r = p * 4 + w;
        float u0 = bf2f(Ygb[r * 136 + lane]);
        float u1 = bf2f(Ygb[r * 136 + lane + 64]);
        float s = wred(u0 + u1);
        float q = wred(u0 * u0 + u1 * u1);
        float mu = s * (1.0f / 128.0f);
        float var = q * (1.0f / 128.0f) - mu * mu;
        float rs = rsqrtf(var + 1e-5f);
        outb[r * 128 + lane] = (u0 - mu) * rs * gl0 + bl0;
        outb[r * 128 + lane + 64] = (u1 - mu) * rs * gl1 + bl1;
    }
}

extern "C" void kernel_launch(void* const* d_in, const int* in_sizes, int n_in,
                              void* d_out, int out_size, void* d_ws, size_t ws_size,
                              hipStream_t stream) {
    const float* hV      = (const float*)d_in[0];
    const float* hE      = (const float*)d_in[1];
    const int*   Eidx    = (const int*)d_in[2];
    const float* maskV   = (const float*)d_in[3];
    const float* maskAtt = (const float*)d_in[4];
    const float* W1  = (const float*)d_in[5];
    const float* b1  = (const float*)d_in[6];
    const float* W2  = (const float*)d_in[7];
    const float* b2  = (const float*)d_in[8];
    const float* W3  = (const float*)d_in[9];
    const float* b3  = (const float*)d_in[10];
    const float* W11 = (const float*)d_in[11];
    const float* b11 = (const float*)d_in[12];
    const float* W12 = (const float*)d_in[13];
    const float* b12 = (const float*)d_in[14];
    const float* W13 = (const float*)d_in[15];
    const float* b13 = (const float*)d_in[16];
    const float* Win = (const float*)d_in[17];
    const float* binp= (const float*)d_in[18];
    const float* Wout= (const float*)d_in[19];
    const float* bout= (const float*)d_in[20];
    const float* g1  = (const float*)d_in[21];
    const float* be1 = (const float*)d_in[22];
    const float* g2  = (const float*)d_in[23];
    const float* be2 = (const float*)d_in[24];
    const float* g3  = (const float*)d_in[25];
    const float* be3 = (const float*)d_in[26];

    char* ws = (char*)d_ws;
    short* Wpk  = (short*)ws;   // packed: 10x16384 (128x128) + 65536 (Win) + 65536 (Wout) shorts
    float* Ys   = (float*)(ws + 1048576);            // 2 MB fp32
    short* Yn   = (short*)(ws + 1048576 + 2097152);  // 1 MB bf16
    float* hv1  = (float*)(ws + 1048576 + 2097152 + 1048576); // 2 MB fp32

    float* hVout = (float*)d_out;
    float* hEout = hVout + 2 * 2048 * 128;

    const int NNODE = 2 * 2048;

    pack_all_kernel<<<144, 256, 0, stream>>>(W1, W2, W3, W11, W12, W13, Win, Wout, Wpk);

    // node precompute: Ys = hV@W1self+b1, Yn = hV@W1nbr
    node_pre_kernel<<<NNODE / 16, 256, 0, stream>>>(hV,
        (const short8*)(Wpk + 98304), (const short8*)(Wpk + 114688), b1, Ys, Yn);

    node_msg_kernel<<<NNODE, 256, 0, stream>>>(hV, hE, Eidx, maskAtt,
        (const short8*)(Wpk), (const short8*)(Wpk + 16384), (const short8*)(Wpk + 32768),
        b2, b3, Ys, Yn, g1, be1, hv1);

    ffn_kernel<<<NNODE / 16, 256, 0, stream>>>(hv1,
        (const short8*)(Wpk + 163840), binp, (const short8*)(Wpk + 229376), bout,
        g2, be2, maskV, hVout);

    // edge precompute on updated nodes
    node_pre_kernel<<<NNODE / 16, 256, 0, stream>>>(hVout,
        (const short8*)(Wpk + 131072), (const short8*)(Wpk + 147456), b11, Ys, Yn);

    edge_upd_kernel<<<NNODE, 256, 0, stream>>>(hE, Eidx,
        (const short8*)(Wpk + 49152), (const short8*)(Wpk + 65536), (const short8*)(Wpk + 81920),
        b12, b13, Ys, Yn, g3, be3, hEout);
}

// Round 5
// 134.927 us; speedup vs baseline: 2.1479x; 1.0500x over previous
//
#include <hip/hip_runtime.h>
#include <hip/hip_bf16.h>

typedef __attribute__((ext_vector_type(8))) short short8;
typedef __attribute__((ext_vector_type(4))) float f32x4;

__device__ inline short f2bf(float f) {
    unsigned u = __builtin_bit_cast(unsigned, f);
    u += 0x7fffu + ((u >> 16) & 1u);
    return (short)(u >> 16);
}
__device__ inline float bf2f(short s) {
    return __builtin_bit_cast(float, ((unsigned)(unsigned short)s) << 16);
}
// packed 2xf32 -> 2xbf16 in one instruction
__device__ inline unsigned cvt_pk_bf16(float a, float b) {
    unsigned r;
    asm("v_cvt_pk_bf16_f32 %0, %1, %2" : "=v"(r) : "v"(a), "v"(b));
    return r;
}
// tanh-form gelu: ~9 VALU ops, max abs err ~3e-3 vs exact
__device__ inline float gelu_fast(float x) {
    float z = x * (1.0f + 0.044715f * x * x);
    float e = __expf(1.5957691216f * z);            // exp(2*0.79788456*z)
    return x - x * __builtin_amdgcn_rcpf(e + 1.0f); // x*(1 - 1/(e+1))
}
__device__ inline float wred(float s) {
#pragma unroll
    for (int o = 32; o; o >>= 1) s += __shfl_xor(s, o, 64);
    return s;
}

// ---- pack all weights into bf16 MFMA-B fragment order -----------------------
// B-frag (16x16x32): lane l holds B[k=(l>>4)*8+j][n=l&15]; slot (nt*Kt+kt)*64+lane.
// (The same packed bytes serve as the A-operand fragment of W^T for the
//  swapped-orientation GEMMs: lane l holds A[m=l&15][k=(l>>4)*8+j].)
__global__ void pack_all_kernel(const float* __restrict__ W1, const float* __restrict__ W2,
                                const float* __restrict__ W3, const float* __restrict__ W11,
                                const float* __restrict__ W12, const float* __restrict__ W13,
                                const float* __restrict__ Win, const float* __restrict__ Wout,
                                short* __restrict__ out) {
    int b = blockIdx.x;
    if (b < 80) {
        int which = b >> 3;
        const float* Ws[10] = {W1 + 128 * 128, W2, W3, W11 + 128 * 128, W12, W13,
                               W1, W1 + 256 * 128, W11, W11 + 256 * 128};
        const float* W = Ws[which];
        int i = (b & 7) * 256 + threadIdx.x;     // 0..2047
        int lane = i & 63, tile = i >> 6;
        int kt = tile & 3, nt = tile >> 2;
        int n = nt * 16 + (lane & 15);
        int k0 = kt * 32 + (lane >> 4) * 8;
        short8 v;
#pragma unroll
        for (int j = 0; j < 8; ++j) v[j] = f2bf(W[(size_t)(k0 + j) * 128 + n]);
        *(short8*)(out + (size_t)which * 16384 + (size_t)i * 8) = v;
    } else if (b < 112) {
        int i = (b - 80) * 256 + threadIdx.x;    // 0..8191
        int lane = i & 63, tile = i >> 6;
        int kt = tile & 3, nt = tile >> 2;       // nt 0..31
        int n = nt * 16 + (lane & 15);
        int k0 = kt * 32 + (lane >> 4) * 8;
        short8 v;
#pragma unroll
        for (int j = 0; j < 8; ++j) v[j] = f2bf(Win[(size_t)(k0 + j) * 512 + n]);
        *(short8*)(out + 163840 + (size_t)i * 8) = v;
    } else {
        int i = (b - 112) * 256 + threadIdx.x;   // 0..8191
        int lane = i & 63, tile = i >> 6;
        int kt = tile & 15, nt = tile >> 4;      // nt 0..7, kt 0..15
        int n = nt * 16 + (lane & 15);
        int k0 = kt * 32 + (lane >> 4) * 8;
        short8 v;
#pragma unroll
        for (int j = 0; j < 8; ++j) v[j] = f2bf(Wout[(size_t)(k0 + j) * 128 + n]);
        *(short8*)(out + 229376 + (size_t)i * 8) = v;
    }
}

// ---- node precompute via MFMA: Ys = x@Wself+b (f32), Yn = x@Wnbr (bf16) -----
__global__ __launch_bounds__(256) void node_pre_kernel(
    const float* __restrict__ hV, const short8* __restrict__ Bs,
    const short8* __restrict__ Bn, const float* __restrict__ bias,
    float* __restrict__ Ys, short* __restrict__ Yn) {
    int n0 = blockIdx.x * 16;
    int tid = threadIdx.x, lane = tid & 63, w = tid >> 6;
    __shared__ __align__(16) short A_sw[16 * 128];
    {
        int off = tid * 8;
        int r = off >> 7, c0 = off & 127;
        const float* src = hV + (size_t)n0 * 128 + off;
        float4 f0 = *(const float4*)(src);
        float4 f1 = *(const float4*)(src + 4);
        uint4 u;
        u.x = cvt_pk_bf16(f0.x, f0.y); u.y = cvt_pk_bf16(f0.z, f0.w);
        u.z = cvt_pk_bf16(f1.x, f1.y); u.w = cvt_pk_bf16(f1.z, f1.w);
        *(uint4*)((char*)A_sw + r * 256 + ((c0 * 2) ^ ((r & 7) << 4))) = u;
    }
    __syncthreads();
    const short8* Bp = (w < 2) ? Bs : Bn;
    f32x4 acc[4];
#pragma unroll
    for (int n2 = 0; n2 < 4; ++n2) acc[n2] = (f32x4){0.f, 0.f, 0.f, 0.f};
#pragma unroll
    for (int kt = 0; kt < 4; ++kt) {
        int row = lane & 15;
        int kb = (kt * 32 + (lane >> 4) * 8) * 2;
        short8 a = *(const short8*)((const char*)A_sw + row * 256 + (kb ^ ((row & 7) << 4)));
#pragma unroll
        for (int n2 = 0; n2 < 4; ++n2) {
            int ntl = (w & 1) * 4 + n2;
            short8 bf = Bp[(ntl * 4 + kt) * 64 + lane];
            acc[n2] = __builtin_amdgcn_mfma_f32_16x16x32_bf16(a, bf, acc[n2], 0, 0, 0);
        }
    }
    if (w < 2) {
#pragma unroll
        for (int n2 = 0; n2 < 4; ++n2) {
            int col = ((w & 1) * 4 + n2) * 16 + (lane & 15);
            float bv = bias[col];
#pragma unroll
            for (int i = 0; i < 4; ++i) {
                int row = (lane >> 4) * 4 + i;
                Ys[(size_t)(n0 + row) * 128 + col] = acc[n2][i] + bv;
            }
        }
    } else {
#pragma unroll
        for (int n2 = 0; n2 < 4; ++n2) {
            int col = ((w & 1) * 4 + n2) * 16 + (lane & 15);
#pragma unroll
            for (int i = 0; i < 4; ++i) {
                int row = (lane >> 4) * 4 + i;
                Yn[(size_t)(n0 + row) * 128 + col] = f2bf(acc[n2][i]);
            }
        }
    }
}

// ---- GEMM helpers on a 48x128 bf16 edge tile in swizzled LDS ---------------
// Tile layout (both read patterns use the same bytes):
//   byte(row=edge, col=feat) = edge*256 + ((feat*2) ^ ((edge&7)<<4))

// old orientation: C[edge][feat] = E @ W ; acc[3 m-tiles][2 n-tiles]
__device__ inline void gemm48_a(const short* A_sw, const short8* __restrict__ Wp,
                                int w, int lane, f32x4 acc[3][2]) {
#pragma unroll
    for (int mt = 0; mt < 3; ++mt)
#pragma unroll
        for (int n2 = 0; n2 < 2; ++n2) acc[mt][n2] = (f32x4){0.f, 0.f, 0.f, 0.f};
#pragma unroll
    for (int kt = 0; kt < 4; ++kt) {
        short8 a[3];
        int kb = (kt * 32 + (lane >> 4) * 8) * 2;
#pragma unroll
        for (int mt = 0; mt < 3; ++mt) {
            int row = mt * 16 + (lane & 15);
            a[mt] = *(const short8*)((const char*)A_sw + row * 256 + (kb ^ ((row & 7) << 4)));
        }
#pragma unroll
        for (int n2 = 0; n2 < 2; ++n2) {
            short8 bf = Wp[((w * 2 + n2) * 4 + kt) * 64 + lane];
#pragma unroll
            for (int mt = 0; mt < 3; ++mt)
                acc[mt][n2] = __builtin_amdgcn_mfma_f32_16x16x32_bf16(a[mt], bf, acc[mt][n2], 0, 0, 0);
        }
    }
}

// swapped orientation: C[feat][edge] = (E@W)^T via mfma(Wfrag, Efrag).
// Per lane: edge = nt*16 + (lane&15); feats = (w*2+m2)*16 + (lane>>4)*4 + i
// -> 4 consecutive feats of one edge = contiguous 8B in the tile.
__device__ inline void gemm48_swz(const short* A_sw, const short8* __restrict__ Wp,
                                  int w, int lane, f32x4 acc[2][3]) {
#pragma unroll
    for (int m2 = 0; m2 < 2; ++m2)
#pragma unroll
        for (int nt = 0; nt < 3; ++nt) acc[m2][nt] = (f32x4){0.f, 0.f, 0.f, 0.f};
#pragma unroll
    for (int kt = 0; kt < 4; ++kt) {
        int kb = (kt * 32 + (lane >> 4) * 8) * 2;
        short8 e[3];
#pragma unroll
        for (int nt = 0; nt < 3; ++nt) {
            int row = nt * 16 + (lane & 15);
            e[nt] = *(const short8*)((const char*)A_sw + row * 256 + (kb ^ ((row & 7) << 4)));
        }
#pragma unroll
        for (int m2 = 0; m2 < 2; ++m2) {
            short8 wf = Wp[((w * 2 + m2) * 4 + kt) * 64 + lane];
#pragma unroll
            for (int nt = 0; nt < 3; ++nt)
                acc[m2][nt] = __builtin_amdgcn_mfma_f32_16x16x32_bf16(wf, e[nt], acc[m2][nt], 0, 0, 0);
        }
    }
}

// stage one node's h_E tile (fp32 global) into bf16 swizzled LDS
__device__ inline void stage_hE(const float* __restrict__ Eb, short* A_sw, int tid) {
#pragma unroll
    for (int i = 0; i < 3; ++i) {
        int e = tid + i * 256;
        int r = e >> 4, c0 = (e & 15) * 8;
        float4 f0 = *(const float4*)(Eb + r * 128 + c0);
        float4 f1 = *(const float4*)(Eb + r * 128 + c0 + 4);
        uint4 u;
        u.x = cvt_pk_bf16(f0.x, f0.y); u.y = cvt_pk_bf16(f0.z, f0.w);
        u.z = cvt_pk_bf16(f1.x, f1.y); u.w = cvt_pk_bf16(f1.z, f1.w);
        *(uint4*)((char*)A_sw + r * 256 + ((c0 * 2) ^ ((r & 7) << 4))) = u;
    }
}

// gather 48 rows of Yn[E_idx] (bf16, 128 cols) into LDS with stride 136
__device__ inline void gather_Yn(const short* __restrict__ Yng, const int* __restrict__ Eidx,
                                 int node, int bb, int tid, short* Ygb) {
    if (tid < 192) {
        int r = tid >> 2, q = tid & 3;
        int idx = Eidx[node * 48 + r];
        const short8* src = (const short8*)(Yng + ((size_t)bb * 2048 + idx) * 128 + q * 32);
        short8* dst = (short8*)(Ygb + r * 136 + q * 32);
        dst[0] = src[0];
        dst[1] = src[1];
        dst[2] = src[2];
        dst[3] = src[3];
    }
}

// layer-1 epilogue (swapped): v = gelu(acc + Ys[feat] + Yn[edge][feat]) -> tile
__device__ inline void epi_l1(f32x4 acc[2][3], const float* Ysh, const short* Ygb,
                              short* A_sw, int w, int lane) {
#pragma unroll
    for (int m2 = 0; m2 < 2; ++m2) {
        int featb = (w * 2 + m2) * 16 + ((lane >> 4) << 2);
        float ys0 = Ysh[featb], ys1 = Ysh[featb + 1];
        float ys2 = Ysh[featb + 2], ys3 = Ysh[featb + 3];
#pragma unroll
        for (int nt = 0; nt < 3; ++nt) {
            int edge = nt * 16 + (lane & 15);
            uint2 yv = *(const uint2*)(Ygb + edge * 136 + featb);
            float v0 = gelu_fast(acc[m2][nt][0] + ys0 + __builtin_bit_cast(float, yv.x << 16));
            float v1 = gelu_fast(acc[m2][nt][1] + ys1 + __builtin_bit_cast(float, yv.x & 0xffff0000u));
            float v2 = gelu_fast(acc[m2][nt][2] + ys2 + __builtin_bit_cast(float, yv.y << 16));
            float v3 = gelu_fast(acc[m2][nt][3] + ys3 + __builtin_bit_cast(float, yv.y & 0xffff0000u));
            uint2 pk = {cvt_pk_bf16(v0, v1), cvt_pk_bf16(v2, v3)};
            *(uint2*)((char*)A_sw + edge * 256 + ((featb * 2) ^ ((edge & 7) << 4))) = pk;
        }
    }
}

// layer-2 epilogue (swapped): v = gelu(acc + b[feat]) -> tile
__device__ inline void epi_l2(f32x4 acc[2][3], const float* __restrict__ b,
                              short* A_sw, int w, int lane) {
#pragma unroll
    for (int m2 = 0; m2 < 2; ++m2) {
        int featb = (w * 2 + m2) * 16 + ((lane >> 4) << 2);
        float b0 = b[featb], b1 = b[featb + 1], b2v = b[featb + 2], b3v = b[featb + 3];
#pragma unroll
        for (int nt = 0; nt < 3; ++nt) {
            int edge = nt * 16 + (lane & 15);
            float v0 = gelu_fast(acc[m2][nt][0] + b0);
            float v1 = gelu_fast(acc[m2][nt][1] + b1);
            float v2 = gelu_fast(acc[m2][nt][2] + b2v);
            float v3 = gelu_fast(acc[m2][nt][3] + b3v);
            uint2 pk = {cvt_pk_bf16(v0, v1), cvt_pk_bf16(v2, v3)};
            *(uint2*)((char*)A_sw + edge * 256 + ((featb * 2) ^ ((edge & 7) << 4))) = pk;
        }
    }
}

// ---- node message MLP + masked mean + LN1 ----------------------------------
__global__ __launch_bounds__(256) void node_msg_kernel(
    const float* __restrict__ hV, const float* __restrict__ hE,
    const int* __restrict__ Eidx, const float* __restrict__ maskAtt,
    const short8* __restrict__ W1bp, const short8* __restrict__ W2p,
    const short8* __restrict__ W3p, const float* __restrict__ b2,
    const float* __restrict__ b3, const float* __restrict__ Ysg,
    const short* __restrict__ Yng, const float* __restrict__ g1,
    const float* __restrict__ be1, float* __restrict__ hv1out) {
    const int node = blockIdx.x;
    const int bb = node >> 11;
    const int tid = threadIdx.x;
    const int lane = tid & 63, w = tid >> 6;

    __shared__ __align__(16) short A_sw[48 * 128];   // 12288 B
    __shared__ __align__(16) short Ygb[48 * 136];    // 13056 B (gathered Yn, bf16)
    __shared__ float Ysh[128];
    __shared__ float mask_s[48];
    __shared__ float red[8];

    stage_hE(hE + (size_t)node * 6144, A_sw, tid);
    if (tid < 128) Ysh[tid] = Ysg[(size_t)node * 128 + tid];
    if (tid >= 128 && tid < 176) mask_s[tid - 128] = maskAtt[node * 48 + tid - 128];
    gather_Yn(Yng, Eidx, node, bb, tid, Ygb);
    __syncthreads();

    f32x4 acc[2][3];
    gemm48_swz(A_sw, W1bp, w, lane, acc);
    __syncthreads();
    epi_l1(acc, Ysh, Ygb, A_sw, w, lane);
    __syncthreads();
    gemm48_swz(A_sw, W2p, w, lane, acc);
    __syncthreads();
    epi_l2(acc, b2, A_sw, w, lane);
    __syncthreads();

    // layer 3 (old orientation) + masked column-sum straight from accumulators
    f32x4 acc3[3][2];
    gemm48_a(A_sw, W3p, w, lane, acc3);
    float u[2];
#pragma unroll
    for (int n2 = 0; n2 < 2; ++n2) {
        int col = (w * 2 + n2) * 16 + (lane & 15);
        float b3c = b3[col];
        float s = 0.f;
#pragma unroll
        for (int mt = 0; mt < 3; ++mt)
#pragma unroll
            for (int i = 0; i < 4; ++i) {
                int row = mt * 16 + (lane >> 4) * 4 + i;
                s += (acc3[mt][n2][i] + b3c) * mask_s[row];
            }
        s += __shfl_xor(s, 16, 64);
        s += __shfl_xor(s, 32, 64);   // total over all 48 rows, replicated
        u[n2] = hV[(size_t)node * 128 + col] + s * (1.0f / 30.0f);
    }
    // LN1 over 128 cols (each wave owns 32 cols, values replicated 4x in-wave)
    float ps = wred(u[0] + u[1]) * 0.25f;
    float pq = wred(u[0] * u[0] + u[1] * u[1]) * 0.25f;
    if (lane == 0) { red[w] = ps; red[4 + w] = pq; }
    __syncthreads();
    float S = red[0] + red[1] + red[2] + red[3];
    float Q = red[4] + red[5] + red[6] + red[7];
    float mu = S * (1.0f / 128.0f);
    float var = Q * (1.0f / 128.0f) - mu * mu;
    float rs = rsqrtf(var + 1e-5f);
    if ((lane >> 4) == 0) {
#pragma unroll
        for (int n2 = 0; n2 < 2; ++n2) {
            int col = (w * 2 + n2) * 16 + (lane & 15);
            hv1out[(size_t)node * 128 + col] = (u[n2] - mu) * rs * g1[col] + be1[col];
        }
    }
}

// ---- FFN via MFMA: [16x128]@[128x512] gelu @[512x128] + residual + LN2 ------
__global__ __launch_bounds__(256) void ffn_kernel(
    const float* __restrict__ hv1, const short8* __restrict__ Winp,
    const float* __restrict__ binp, const short8* __restrict__ Woutp,
    const float* __restrict__ bout, const float* __restrict__ g2,
    const float* __restrict__ be2, const float* __restrict__ maskV,
    float* __restrict__ hVout) {
    int n0 = blockIdx.x * 16;
    int tid = threadIdx.x, lane = tid & 63, w = tid >> 6;
    __shared__ float X[16 * 128];                    // 8 KB fp32 (residual + pre-LN)
    __shared__ __align__(16) short A_sw[16 * 128];   // 4 KB bf16 swizzled
    __shared__ __align__(16) short H_sw[16 * 512];   // 16 KB bf16 swizzled

    {
        int off = tid * 8;
        int r = off >> 7, c0 = off & 127;
        const float* src = hv1 + (size_t)n0 * 128 + off;
        float4 f0 = *(const float4*)(src);
        float4 f1 = *(const float4*)(src + 4);
        *(float4*)(&X[off]) = f0;
        *(float4*)(&X[off + 4]) = f1;
        uint4 u;
        u.x = cvt_pk_bf16(f0.x, f0.y); u.y = cvt_pk_bf16(f0.z, f0.w);
        u.z = cvt_pk_bf16(f1.x, f1.y); u.w = cvt_pk_bf16(f1.z, f1.w);
        *(uint4*)((char*)A_sw + r * 256 + ((c0 * 2) ^ ((r & 7) << 4))) = u;
    }
    __syncthreads();

    // GEMM1: each wave covers n-tiles w*8..w*8+7 of 32
    f32x4 acc1[8];
#pragma unroll
    for (int n2 = 0; n2 < 8; ++n2) acc1[n2] = (f32x4){0.f, 0.f, 0.f, 0.f};
#pragma unroll
    for (int kt = 0; kt < 4; ++kt) {
        int row = lane & 15;
        int kb = (kt * 32 + (lane >> 4) * 8) * 2;
        short8 a = *(const short8*)((const char*)A_sw + row * 256 + (kb ^ ((row & 7) << 4)));
#pragma unroll
        for (int n2 = 0; n2 < 8; ++n2) {
            short8 bf = Winp[((w * 8 + n2) * 4 + kt) * 64 + lane];
            acc1[n2] = __builtin_amdgcn_mfma_f32_16x16x32_bf16(a, bf, acc1[n2], 0, 0, 0);
        }
    }
#pragma unroll
    for (int n2 = 0; n2 < 8; ++n2) {
        int col = (w * 8 + n2) * 16 + (lane & 15);
        float bv = binp[col];
#pragma unroll
        for (int i = 0; i < 4; ++i) {
            int row = (lane >> 4) * 4 + i;
            float v = gelu_fast(acc1[n2][i] + bv);
            *(short*)((char*)H_sw + row * 1024 + ((col * 2) ^ ((row & 7) << 4))) = f2bf(v);
        }
    }
    __syncthreads();

    // GEMM2: each wave covers n-tiles w*2, w*2+1 of 8
    f32x4 acc2[2];
    acc2[0] = (f32x4){0.f, 0.f, 0.f, 0.f};
    acc2[1] = (f32x4){0.f, 0.f, 0.f, 0.f};
#pragma unroll
    for (int kt = 0; kt < 16; ++kt) {
        int row = lane & 15;
        int kb = (kt * 32 + (lane >> 4) * 8) * 2;
        short8 a = *(const short8*)((const char*)H_sw + row * 1024 + (kb ^ ((row & 7) << 4)));
#pragma unroll
        for (int n2 = 0; n2 < 2; ++n2) {
            short8 bf = Woutp[((w * 2 + n2) * 16 + kt) * 64 + lane];
            acc2[n2] = __builtin_amdgcn_mfma_f32_16x16x32_bf16(a, bf, acc2[n2], 0, 0, 0);
        }
    }
#pragma unroll
    for (int n2 = 0; n2 < 2; ++n2) {
        int col = (w * 2 + n2) * 16 + (lane & 15);
        float bo = bout[col];
#pragma unroll
        for (int i = 0; i < 4; ++i) {
            int row = (lane >> 4) * 4 + i;
            X[row * 128 + col] += acc2[n2][i] + bo;
        }
    }
    __syncthreads();

#pragma unroll
    for (int p = 0; p < 4; ++p) {
        int r = p * 4 + w;
        float u0 = X[r * 128 + lane], u1 = X[r * 128 + lane + 64];
        float s = wred(u0 + u1);
        float q = wred(u0 * u0 + u1 * u1);
        float mu = s * (1.0f / 128.0f);
        float var = q * (1.0f / 128.0f) - mu * mu;
        float rs = rsqrtf(var + 1e-5f);
        float mv = maskV[n0 + r];
        hVout[(size_t)(n0 + r) * 128 + lane] = mv * ((u0 - mu) * rs * g2[lane] + be2[lane]);
        hVout[(size_t)(n0 + r) * 128 + lane + 64] = mv * ((u1 - mu) * rs * g2[lane + 64] + be2[lane + 64]);
    }
}

// ---- edge update MLP + residual + LN3 ---------------------------------------
__global__ __launch_bounds__(256) void edge_upd_kernel(
    const float* __restrict__ hE, const int* __restrict__ Eidx,
    const short8* __restrict__ W11bp, const short8* __restrict__ W12p,
    const short8* __restrict__ W13p, const float* __restrict__ b12,
    const float* __restrict__ b13, const float* __restrict__ Ysg,
    const short* __restrict__ Yng, const float* __restrict__ g3,
    const float* __restrict__ be3, float* __restrict__ hEout) {
    const int node = blockIdx.x;
    const int bb = node >> 11;
    const int tid = threadIdx.x;
    const int lane = tid & 63, w = tid >> 6;

    __shared__ __align__(16) short A_sw[48 * 128];   // 12288 B
    __shared__ __align__(16) short Ygb[48 * 136];    // gather, then pre-LN stash
    __shared__ float Ysh[128];

    const float* Eb = hE + (size_t)node * 6144;
    stage_hE(Eb, A_sw, tid);
    if (tid < 128) Ysh[tid] = Ysg[(size_t)node * 128 + tid];
    gather_Yn(Yng, Eidx, node, bb, tid, Ygb);
    __syncthreads();

    f32x4 acc[2][3];
    gemm48_swz(A_sw, W11bp, w, lane, acc);
    __syncthreads();
    epi_l1(acc, Ysh, Ygb, A_sw, w, lane);
    __syncthreads();
    gemm48_swz(A_sw, W12p, w, lane, acc);
    __syncthreads();
    epi_l2(acc, b12, A_sw, w, lane);
    __syncthreads();

    // layer 3 (old orientation): pre-LN = msg + b13 + residual(re-read fp32)
    f32x4 acc3[3][2];
    gemm48_a(A_sw, W13p, w, lane, acc3);
#pragma unroll
    for (int mt = 0; mt < 3; ++mt)
#pragma unroll
        for (int n2 = 0; n2 < 2; ++n2) {
            int col = (w * 2 + n2) * 16 + (lane & 15);
            float bv = b13[col];
#pragma unroll
            for (int i = 0; i < 4; ++i) {
                int row = mt * 16 + (lane >> 4) * 4 + i;
                float v = acc3[mt][n2][i] + bv + Eb[row * 128 + col];
                Ygb[row * 136 + col] = f2bf(v);
            }
        }
    __syncthreads();

    // LN per edge row (wave per row), coalesced output
    float* outb = hEout + (size_t)node * 6144;
    float gl0 = g3[lane], gl1 = g3[lane + 64];
    float bl0 = be3[lane], bl1 = be3[lane + 64];
#pragma unroll
    for (int p = 0; p < 12; ++p) {
        int r = p * 4 + w;
        float u0 = bf2f(Ygb[r * 136 + lane]);
        float u1 = bf2f(Ygb[r * 136 + lane + 64]);
        float s = wred(u0 + u1);
        float q = wred(u0 * u0 + u1 * u1);
        float mu = s * (1.0f / 128.0f);
        float var = q * (1.0f / 128.0f) - mu * mu;
        float rs = rsqrtf(var + 1e-5f);
        outb[r * 128 + lane] = (u0 - mu) * rs * gl0 + bl0;
        outb[r * 128 + lane + 64] = (u1 - mu) * rs * gl1 + bl1;
    }
}

extern "C" void kernel_launch(void* const* d_in, const int* in_sizes, int n_in,
                              void* d_out, int out_size, void* d_ws, size_t ws_size,
                              hipStream_t stream) {
    const float* hV      = (const float*)d_in[0];
    const float* hE      = (const float*)d_in[1];
    const int*   Eidx    = (const int*)d_in[2];
    const float* maskV   = (const float*)d_in[3];
    const float* maskAtt = (const float*)d_in[4];
    const float* W1  = (const float*)d_in[5];
    const float* b1  = (const float*)d_in[6];
    const float* W2  = (const float*)d_in[7];
    const float* b2  = (const float*)d_in[8];
    const float* W3  = (const float*)d_in[9];
    const float* b3  = (const float*)d_in[10];
    const float* W11 = (const float*)d_in[11];
    const float* b11 = (const float*)d_in[12];
    const float* W12 = (const float*)d_in[13];
    const float* b12 = (const float*)d_in[14];
    const float* W13 = (const float*)d_in[15];
    const float* b13 = (const float*)d_in[16];
    const float* Win = (const float*)d_in[17];
    const float* binp= (const float*)d_in[18];
    const float* Wout= (const float*)d_in[19];
    const float* bout= (const float*)d_in[20];
    const float* g1  = (const float*)d_in[21];
    const float* be1 = (const float*)d_in[22];
    const float* g2  = (const float*)d_in[23];
    const float* be2 = (const float*)d_in[24];
    const float* g3  = (const float*)d_in[25];
    const float* be3 = (const float*)d_in[26];

    char* ws = (char*)d_ws;
    short* Wpk  = (short*)ws;   // packed: 10x16384 (128x128) + 65536 (Win) + 65536 (Wout) shorts
    float* Ys   = (float*)(ws + 1048576);            // 2 MB fp32
    short* Yn   = (short*)(ws + 1048576 + 2097152);  // 1 MB bf16
    float* hv1  = (float*)(ws + 1048576 + 2097152 + 1048576); // 2 MB fp32

    float* hVout = (float*)d_out;
    float* hEout = hVout + 2 * 2048 * 128;

    const int NNODE = 2 * 2048;

    pack_all_kernel<<<144, 256, 0, stream>>>(W1, W2, W3, W11, W12, W13, Win, Wout, Wpk);

    node_pre_kernel<<<NNODE / 16, 256, 0, stream>>>(hV,
        (const short8*)(Wpk + 98304), (const short8*)(Wpk + 114688), b1, Ys, Yn);

    node_msg_kernel<<<NNODE, 256, 0, stream>>>(hV, hE, Eidx, maskAtt,
        (const short8*)(Wpk), (const short8*)(Wpk + 16384), (const short8*)(Wpk + 32768),
        b2, b3, Ys, Yn, g1, be1, hv1);

    ffn_kernel<<<NNODE / 16, 256, 0, stream>>>(hv1,
        (const short8*)(Wpk + 163840), binp, (const short8*)(Wpk + 229376), bout,
        g2, be2, maskV, hVout);

    node_pre_kernel<<<NNODE / 16, 256, 0, stream>>>(hVout,
        (const short8*)(Wpk + 131072), (const short8*)(Wpk + 147456), b11, Ys, Yn);

    edge_upd_kernel<<<NNODE, 256, 0, stream>>>(hE, Eidx,
        (const short8*)(Wpk + 49152), (const short8*)(Wpk + 65536), (const short8*)(Wpk + 81920),
        b12, b13, Ys, Yn, g3, be3, hEout);
}